// Round 3
// baseline (2674.038 us; speedup 1.0000x reference)
//
#include <hip/hip_runtime.h>
#include <hip/hip_bf16.h>

// ---- problem constants ----
#define B_SZ 4
#define S_SZ 2048
#define DM   1024
#define NH   8
#define DK   128
#define DC   32
#define DHR  32
#define DQK  160            // DK + DHR
#define T_TOK (B_SZ * S_SZ) // 8192
#define SCALE 0.07905694150420949f // 1/sqrt(160)

typedef unsigned int uint;
typedef unsigned short ushort;

__device__ __forceinline__ float bf_lo(uint u) { return __uint_as_float(u << 16); }
__device__ __forceinline__ float bf_hi(uint u) { return __uint_as_float(u & 0xffff0000u); }
__device__ __forceinline__ ushort f2bf(float f) {
    uint u = __float_as_uint(f);
    uint r = u + 0x7fffu + ((u >> 16) & 1u);
    return (ushort)(r >> 16);
}
__device__ __forceinline__ uint packbf(float x, float y) {
    return (uint)f2bf(x) | ((uint)f2bf(y) << 16);
}

// ============================================================
// Kernel 1: c_q, c_kv, k_r  = h_t @ {W_DQ, W_DKV, W_KR} + bias
// h_t [T,1024] fp32; W [1024,32] fp32; out fp32 [T,32] each.
// Block: 256 thr handles 32 tokens. Grid: T/32 = 256.
// ============================================================
__global__ __launch_bounds__(256) void latent_kernel(
    const float* __restrict__ h_t,
    const float* __restrict__ W_DQ, const float* __restrict__ b_DQ,
    const float* __restrict__ W_DKV, const float* __restrict__ b_DKV,
    const float* __restrict__ W_KR, const float* __restrict__ b_KR,
    float* __restrict__ c_q, float* __restrict__ c_kv, float* __restrict__ k_r)
{
    __shared__ __align__(16) float hs[32 * 33];
    __shared__ __align__(16) float wq[32 * 32];
    __shared__ __align__(16) float wkv[32 * 32];
    __shared__ __align__(16) float wkr[32 * 32];

    const int tid = threadIdx.x;
    const int t0 = blockIdx.x * 32;
    const int t = tid & 31;     // token within tile
    const int g = tid >> 5;     // col group 0..7 (4 cols each)

    float acc_q[4] = {0.f, 0.f, 0.f, 0.f};
    float acc_kv[4] = {0.f, 0.f, 0.f, 0.f};
    float acc_kr[4] = {0.f, 0.f, 0.f, 0.f};

    const int lr = tid >> 3;    // 0..31 (row for loads)
    const int lc = (tid & 7) * 4; // 0..28 (col*4 for loads)

    for (int k0 = 0; k0 < DM; k0 += 32) {
        __syncthreads();
        // h tile: 32 tokens x 32 k (256 float4 loads)
        {
            float4 v = *(const float4*)&h_t[(size_t)(t0 + lr) * DM + k0 + lc];
            hs[lr * 33 + lc + 0] = v.x;
            hs[lr * 33 + lc + 1] = v.y;
            hs[lr * 33 + lc + 2] = v.z;
            hs[lr * 33 + lc + 3] = v.w;
        }
        // weight tiles: [32 k][32 cols], 256 float4 each
        {
            float4 a = *(const float4*)&W_DQ[(size_t)(k0 + lr) * 32 + lc];
            wq[lr * 32 + lc + 0] = a.x; wq[lr * 32 + lc + 1] = a.y;
            wq[lr * 32 + lc + 2] = a.z; wq[lr * 32 + lc + 3] = a.w;
            float4 b = *(const float4*)&W_DKV[(size_t)(k0 + lr) * 32 + lc];
            wkv[lr * 32 + lc + 0] = b.x; wkv[lr * 32 + lc + 1] = b.y;
            wkv[lr * 32 + lc + 2] = b.z; wkv[lr * 32 + lc + 3] = b.w;
            float4 c = *(const float4*)&W_KR[(size_t)(k0 + lr) * 32 + lc];
            wkr[lr * 32 + lc + 0] = c.x; wkr[lr * 32 + lc + 1] = c.y;
            wkr[lr * 32 + lc + 2] = c.z; wkr[lr * 32 + lc + 3] = c.w;
        }
        __syncthreads();
        #pragma unroll 8
        for (int kk = 0; kk < 32; ++kk) {
            float a = hs[t * 33 + kk];
            #pragma unroll
            for (int cc = 0; cc < 4; ++cc) {
                int c = g * 4 + cc;
                acc_q[cc] += a * wq[kk * 32 + c];
                acc_kv[cc] += a * wkv[kk * 32 + c];
                acc_kr[cc] += a * wkr[kk * 32 + c];
            }
        }
    }
    #pragma unroll
    for (int cc = 0; cc < 4; ++cc) {
        int c = g * 4 + cc;
        int idx = (t0 + t) * 32 + c;
        c_q[idx] = acc_q[cc] + b_DQ[c];
        c_kv[idx] = acc_kv[cc] + b_DKV[c];
        k_r[idx] = acc_kr[cc] + b_KR[c];
    }
}

// ============================================================
// Kernel 2: build q, k, v (bf16) in [bh][s][d] layout.
// q[bh][s][0:128]=c_q@W_UQ+b ; q[...][128:160]=c_q@W_QR+b
// k[bh][s][0:128]=c_kv@W_UK+b ; k[...][128:160]=k_r (shared)
// v[bh][s][0:128]=c_kv@W_UV+b
// Block: 256 thr, 16 tokens, loops 14x over 3584 per-token outputs.
// Grid: T/16 = 512.
// ============================================================
__global__ __launch_bounds__(256) void build_qkv_kernel(
    const float* __restrict__ c_q, const float* __restrict__ c_kv,
    const float* __restrict__ k_r,
    const float* __restrict__ W_UQ, const float* __restrict__ b_UQ,
    const float* __restrict__ W_UK, const float* __restrict__ b_UK,
    const float* __restrict__ W_UV, const float* __restrict__ b_UV,
    const float* __restrict__ W_QR, const float* __restrict__ b_QR,
    ushort* __restrict__ q_ws, ushort* __restrict__ k_ws, ushort* __restrict__ v_ws)
{
    __shared__ __align__(16) float cb[16 * 96]; // [token][c_q(32) | c_kv(32) | k_r(32)]
    const int tid = threadIdx.x;
    const int t0 = blockIdx.x * 16;

    for (int i = tid; i < 512; i += 256) {
        int tt = i >> 5, c = i & 31;
        cb[tt * 96 + c] = c_q[(t0 + tt) * 32 + c];
        cb[tt * 96 + 32 + c] = c_kv[(t0 + tt) * 32 + c];
        cb[tt * 96 + 64 + c] = k_r[(t0 + tt) * 32 + c];
    }
    __syncthreads();

    for (int i = 0; i < 14; ++i) {
        int e = i * 256 + tid;      // 0..3583
        int h = e / 448;
        int r = e - h * 448;

        float acc[16];
        if (r >= 288 && r < 320) {
            // k_r copy (already biased)
            #pragma unroll
            for (int tt = 0; tt < 16; ++tt) acc[tt] = cb[tt * 96 + 64 + (r - 288)];
        } else {
            const float* W; const float* bias; int stride, col, coff;
            if (r < 128)      { W = W_UQ; stride = 1024; col = h * 128 + r;        coff = 0;  bias = b_UQ; }
            else if (r < 160) { W = W_QR; stride = 256;  col = h * 32 + (r - 128); coff = 0;  bias = b_QR; }
            else if (r < 288) { W = W_UK; stride = 1024; col = h * 128 + (r - 160);coff = 32; bias = b_UK; }
            else              { W = W_UV; stride = 1024; col = h * 128 + (r - 320);coff = 32; bias = b_UV; }
            float bv = bias[col];
            #pragma unroll
            for (int tt = 0; tt < 16; ++tt) acc[tt] = bv;
            for (int kk = 0; kk < 32; ++kk) {
                float w = W[kk * stride + col];
                #pragma unroll
                for (int tt = 0; tt < 16; ++tt) acc[tt] += cb[tt * 96 + coff + kk] * w;
            }
        }
        #pragma unroll
        for (int tt = 0; tt < 16; ++tt) {
            int tok = t0 + tt;
            int b = tok >> 11, s = tok & 2047;
            int bh = b * NH + h;
            ushort val = f2bf(acc[tt]);
            if (r < 160)      q_ws[((size_t)bh * S_SZ + s) * DQK + r] = val;
            else if (r < 320) k_ws[((size_t)bh * S_SZ + s) * DQK + (r - 160)] = val;
            else              v_ws[((size_t)bh * S_SZ + s) * DK + (r - 320)] = val;
        }
    }
}

// ============================================================
// Kernel 3: flash-style attention per (bh, 64-row Q tile).
// Online softmax, fp32 accumulation, bf16 LDS tiles, b128 reads.
// Block 256 thr: scores: (qr=tid>>2, 8 keys per thread);
//                PV:     (qr=tid>>2, 32 dims = (tid&3)*32..).
// Grid: (S/64, B*H) = (32, 32).
// ============================================================
__global__ __launch_bounds__(256) void attn_kernel(
    const ushort* __restrict__ q_ws, const ushort* __restrict__ k_ws,
    const ushort* __restrict__ v_ws, ushort* __restrict__ o_ws)
{
    // u32-packed bf16 pairs; rows padded for banks + 16B alignment
    __shared__ __align__(16) uint Qt[64 * 84];  // 64 rows x 80 u32 (160 bf16)
    __shared__ __align__(16) uint Kt[32 * 84];  // 32 rows x 80 u32
    __shared__ __align__(16) uint Vt[32 * 68];  // 32 rows x 64 u32 (128 bf16)
    __shared__ __align__(16) float Pl[64 * 36]; // 64 rows x 32 probs

    const int tid = threadIdx.x;
    const int qtile = blockIdx.x;
    const int bh = blockIdx.y;
    const int b = bh >> 3, h = bh & 7;
    const int s0 = qtile * 64;

    const uint* qsrc = (const uint*)q_ws + ((size_t)bh * S_SZ + s0) * 80;
    const uint* ksrc = (const uint*)k_ws + (size_t)bh * S_SZ * 80;
    const uint* vsrc = (const uint*)v_ws + (size_t)bh * S_SZ * 64;

    // load Q tile (64 x 80 u32)
    for (int i = tid; i < 64 * 80; i += 256) {
        int row = i / 80, col = i - row * 80;
        Qt[row * 84 + col] = qsrc[row * 80 + col];
    }

    const int qr = tid >> 2;   // 0..63
    const int kq = tid & 3;    // 0..3

    float m_run = -3.0e38f, l_run = 0.f;
    float o_acc[32];
    #pragma unroll
    for (int d = 0; d < 32; ++d) o_acc[d] = 0.f;

    for (int kt = 0; kt < S_SZ / 32; ++kt) {
        const int kt0 = kt * 32;
        __syncthreads(); // prior PV done before overwriting K/V
        for (int i = tid; i < 32 * 80; i += 256) {
            int row = i / 80, col = i - row * 80;
            Kt[row * 84 + col] = ksrc[(kt0 + row) * 80 + col];
        }
        for (int i = tid; i < 32 * 64; i += 256) {
            int row = i >> 6, col = i & 63;
            Vt[row * 68 + col] = vsrc[(kt0 + row) * 64 + col];
        }
        __syncthreads();

        // ---- scores: 8 keys per thread ----
        float s[8];
        #pragma unroll
        for (int j = 0; j < 8; ++j) s[j] = 0.f;
        for (int d4 = 0; d4 < 20; ++d4) {
            uint4 qv = *(const uint4*)&Qt[qr * 84 + d4 * 4];
            float q0 = bf_lo(qv.x), q1 = bf_hi(qv.x), q2 = bf_lo(qv.y), q3 = bf_hi(qv.y);
            float q4 = bf_lo(qv.z), q5 = bf_hi(qv.z), q6 = bf_lo(qv.w), q7 = bf_hi(qv.w);
            #pragma unroll
            for (int j = 0; j < 8; ++j) {
                uint4 kv = *(const uint4*)&Kt[(kq + 4 * j) * 84 + d4 * 4];
                s[j] += q0 * bf_lo(kv.x) + q1 * bf_hi(kv.x)
                      + q2 * bf_lo(kv.y) + q3 * bf_hi(kv.y)
                      + q4 * bf_lo(kv.z) + q5 * bf_hi(kv.z)
                      + q6 * bf_lo(kv.w) + q7 * bf_hi(kv.w);
            }
        }
        float tmax = -3.0e38f;
        #pragma unroll
        for (int j = 0; j < 8; ++j) { s[j] *= SCALE; tmax = fmaxf(tmax, s[j]); }
        tmax = fmaxf(tmax, __shfl_xor(tmax, 1));
        tmax = fmaxf(tmax, __shfl_xor(tmax, 2));

        float m_new = fmaxf(m_run, tmax);
        float alpha = __expf(m_run - m_new);
        m_run = m_new;

        float psum = 0.f;
        #pragma unroll
        for (int j = 0; j < 8; ++j) {
            float p = __expf(s[j] - m_new);
            Pl[qr * 36 + kq + 4 * j] = p;
            psum += p;
        }
        psum += __shfl_xor(psum, 1);
        psum += __shfl_xor(psum, 2);
        l_run = l_run * alpha + psum;

        #pragma unroll
        for (int d = 0; d < 32; ++d) o_acc[d] *= alpha;

        __syncthreads(); // P visible

        // ---- PV: 32 dims per thread over 32 keys ----
        #pragma unroll 2
        for (int kk = 0; kk < 8; ++kk) {
            float4 p4 = *(const float4*)&Pl[qr * 36 + kk * 4];
            float pv[4] = {p4.x, p4.y, p4.z, p4.w};
            #pragma unroll
            for (int c = 0; c < 4; ++c) {
                int key = kk * 4 + c;
                const uint* vrow = &Vt[key * 68 + kq * 16];
                #pragma unroll
                for (int ii = 0; ii < 4; ++ii) {
                    uint4 vv = *(const uint4*)(vrow + ii * 4);
                    o_acc[ii * 8 + 0] += pv[c] * bf_lo(vv.x);
                    o_acc[ii * 8 + 1] += pv[c] * bf_hi(vv.x);
                    o_acc[ii * 8 + 2] += pv[c] * bf_lo(vv.y);
                    o_acc[ii * 8 + 3] += pv[c] * bf_hi(vv.y);
                    o_acc[ii * 8 + 4] += pv[c] * bf_lo(vv.z);
                    o_acc[ii * 8 + 5] += pv[c] * bf_hi(vv.z);
                    o_acc[ii * 8 + 6] += pv[c] * bf_lo(vv.w);
                    o_acc[ii * 8 + 7] += pv[c] * bf_hi(vv.w);
                }
            }
        }
    }

    // write O in [b, s, h, d] layout (token-major rows for final GEMM)
    float inv_l = 1.0f / l_run;
    size_t base = (((size_t)(b * S_SZ + s0 + qr) * NH) + h) * DK + kq * 32;
    uint* op = (uint*)o_ws + (base >> 1);
    #pragma unroll
    for (int i = 0; i < 16; ++i)
        op[i] = packbf(o_acc[2 * i] * inv_l, o_acc[2 * i + 1] * inv_l);
}

// ============================================================
// Kernel 4: out = o_ws [8192,1024](bf16) @ W_O [1024,1024](fp32) + b_O
// 64x64 tile per block, 4x4 per thread, K-tile 32, fp32 VALU, fp32 out.
// Grid: (1024/64, 8192/64) = (16, 128).
// ============================================================
__global__ __launch_bounds__(256) void out_gemm_kernel(
    const ushort* __restrict__ o_ws, const float* __restrict__ W_O,
    const float* __restrict__ b_O, float* __restrict__ out)
{
    __shared__ __align__(16) float Ast[32 * 68]; // [kk][row]
    __shared__ __align__(16) float Bs[32 * 68];  // [kk][col]

    const int tid = threadIdx.x;
    const int n0 = blockIdx.x * 64;
    const int m0 = blockIdx.y * 64;
    const int tx = tid & 15, ty = tid >> 4;

    float acc[4][4];
    #pragma unroll
    for (int i = 0; i < 4; ++i)
        #pragma unroll
        for (int j = 0; j < 4; ++j) acc[i][j] = 0.f;

    const uint* Au = (const uint*)o_ws;

    for (int k0 = 0; k0 < DM; k0 += 32) {
        __syncthreads();
        // A tile: 64 rows x 32 k of bf16 (1024 uints)
        for (int i = tid; i < 1024; i += 256) {
            int r = i >> 4, c2 = i & 15;
            uint v = Au[(size_t)(m0 + r) * (DM / 2) + (k0 >> 1) + c2];
            Ast[(2 * c2) * 68 + r] = bf_lo(v);
            Ast[(2 * c2 + 1) * 68 + r] = bf_hi(v);
        }
        // B tile: 32 k x 64 n of fp32 (512 float4)
        for (int i = tid; i < 512; i += 256) {
            int r = i >> 4, c4 = (i & 15) * 4;
            float4 v = *(const float4*)&W_O[(size_t)(k0 + r) * DM + n0 + c4];
            Bs[r * 68 + c4 + 0] = v.x;
            Bs[r * 68 + c4 + 1] = v.y;
            Bs[r * 68 + c4 + 2] = v.z;
            Bs[r * 68 + c4 + 3] = v.w;
        }
        __syncthreads();
        #pragma unroll 8
        for (int kk = 0; kk < 32; ++kk) {
            float4 a4 = *(const float4*)&Ast[kk * 68 + ty * 4];
            float4 b4 = *(const float4*)&Bs[kk * 68 + tx * 4];
            float av[4] = {a4.x, a4.y, a4.z, a4.w};
            float bv[4] = {b4.x, b4.y, b4.z, b4.w};
            #pragma unroll
            for (int i = 0; i < 4; ++i)
                #pragma unroll
                for (int j = 0; j < 4; ++j) acc[i][j] += av[i] * bv[j];
        }
    }

    float bo[4];
    #pragma unroll
    for (int j = 0; j < 4; ++j) bo[j] = b_O[n0 + tx * 4 + j];
    #pragma unroll
    for (int i = 0; i < 4; ++i) {
        int row = m0 + ty * 4 + i;
        #pragma unroll
        for (int j = 0; j < 4; ++j) {
            out[(size_t)row * DM + n0 + tx * 4 + j] = acc[i][j] + bo[j];
        }
    }
}

// ============================================================
extern "C" void kernel_launch(void* const* d_in, const int* in_sizes, int n_in,
                              void* d_out, int out_size, void* d_ws, size_t ws_size,
                              hipStream_t stream) {
    (void)in_sizes; (void)n_in; (void)out_size; (void)ws_size;

    const float* h_t   = (const float*)d_in[0];
    const float* W_DQ  = (const float*)d_in[1];
    const float* b_DQ  = (const float*)d_in[2];
    const float* W_UQ  = (const float*)d_in[3];
    const float* b_UQ  = (const float*)d_in[4];
    const float* W_DKV = (const float*)d_in[5];
    const float* b_DKV = (const float*)d_in[6];
    const float* W_UK  = (const float*)d_in[7];
    const float* b_UK  = (const float*)d_in[8];
    const float* W_UV  = (const float*)d_in[9];
    const float* b_UV  = (const float*)d_in[10];
    const float* W_QR  = (const float*)d_in[11];
    const float* b_QR  = (const float*)d_in[12];
    const float* W_KR  = (const float*)d_in[13];
    const float* b_KR  = (const float*)d_in[14];
    const float* W_O   = (const float*)d_in[15];
    const float* b_O   = (const float*)d_in[16];

    // workspace carve: 3*1MB fp32 latents + 21+21+16.8+16.8 MB bf16 = ~79MB
    float* c_q  = (float*)d_ws;
    float* c_kv = c_q + T_TOK * DC;
    float* k_r  = c_kv + T_TOK * DC;
    ushort* q_ws = (ushort*)(k_r + T_TOK * DC);
    ushort* k_ws = q_ws + (size_t)B_SZ * NH * S_SZ * DQK;
    ushort* v_ws = k_ws + (size_t)B_SZ * NH * S_SZ * DQK;
    ushort* o_ws = v_ws + (size_t)B_SZ * NH * S_SZ * DK;

    float* out = (float*)d_out;

    latent_kernel<<<T_TOK / 32, 256, 0, stream>>>(
        h_t, W_DQ, b_DQ, W_DKV, b_DKV, W_KR, b_KR, c_q, c_kv, k_r);

    build_qkv_kernel<<<T_TOK / 16, 256, 0, stream>>>(
        c_q, c_kv, k_r, W_UQ, b_UQ, W_UK, b_UK, W_UV, b_UV, W_QR, b_QR,
        q_ws, k_ws, v_ws);

    attn_kernel<<<dim3(S_SZ / 64, B_SZ * NH), 256, 0, stream>>>(
        q_ws, k_ws, v_ws, o_ws);

    out_gemm_kernel<<<dim3(DM / 64, T_TOK / 64), 256, 0, stream>>>(
        o_ws, W_O, b_O, out);
}

// Round 4
// 639.387 us; speedup vs baseline: 4.1822x; 4.1822x over previous
//
#include <hip/hip_runtime.h>
#include <hip/hip_bf16.h>

// ---- problem constants ----
#define B_SZ 4
#define S_SZ 2048
#define DM   1024
#define NH   8
#define DK   128
#define DC   32
#define DHR  32
#define DQK  160            // DK + DHR
#define T_TOK (B_SZ * S_SZ) // 8192
#define SCALE 0.07905694150420949f // 1/sqrt(160)

typedef unsigned int uint;
typedef unsigned short ushort;
typedef __attribute__((ext_vector_type(8))) short short8;
typedef __attribute__((ext_vector_type(4))) float floatx4;

__device__ __forceinline__ float bf_lo(uint u) { return __uint_as_float(u << 16); }
__device__ __forceinline__ float bf_hi(uint u) { return __uint_as_float(u & 0xffff0000u); }
__device__ __forceinline__ ushort f2bf(float f) {
    uint u = __float_as_uint(f);
    uint r = u + 0x7fffu + ((u >> 16) & 1u);
    return (ushort)(r >> 16);
}
__device__ __forceinline__ uint packbf(float x, float y) {
    return (uint)f2bf(x) | ((uint)f2bf(y) << 16);
}

// ============================================================
// Kernel 1: c_q, c_kv, k_r  = h_t @ {W_DQ, W_DKV, W_KR} + bias
// (unchanged from round 3)
// ============================================================
__global__ __launch_bounds__(256) void latent_kernel(
    const float* __restrict__ h_t,
    const float* __restrict__ W_DQ, const float* __restrict__ b_DQ,
    const float* __restrict__ W_DKV, const float* __restrict__ b_DKV,
    const float* __restrict__ W_KR, const float* __restrict__ b_KR,
    float* __restrict__ c_q, float* __restrict__ c_kv, float* __restrict__ k_r)
{
    __shared__ __align__(16) float hs[32 * 33];
    __shared__ __align__(16) float wq[32 * 32];
    __shared__ __align__(16) float wkv[32 * 32];
    __shared__ __align__(16) float wkr[32 * 32];

    const int tid = threadIdx.x;
    const int t0 = blockIdx.x * 32;
    const int t = tid & 31;
    const int g = tid >> 5;

    float acc_q[4] = {0.f, 0.f, 0.f, 0.f};
    float acc_kv[4] = {0.f, 0.f, 0.f, 0.f};
    float acc_kr[4] = {0.f, 0.f, 0.f, 0.f};

    const int lr = tid >> 3;
    const int lc = (tid & 7) * 4;

    for (int k0 = 0; k0 < DM; k0 += 32) {
        __syncthreads();
        {
            float4 v = *(const float4*)&h_t[(size_t)(t0 + lr) * DM + k0 + lc];
            hs[lr * 33 + lc + 0] = v.x;
            hs[lr * 33 + lc + 1] = v.y;
            hs[lr * 33 + lc + 2] = v.z;
            hs[lr * 33 + lc + 3] = v.w;
        }
        {
            float4 a = *(const float4*)&W_DQ[(size_t)(k0 + lr) * 32 + lc];
            wq[lr * 32 + lc + 0] = a.x; wq[lr * 32 + lc + 1] = a.y;
            wq[lr * 32 + lc + 2] = a.z; wq[lr * 32 + lc + 3] = a.w;
            float4 b = *(const float4*)&W_DKV[(size_t)(k0 + lr) * 32 + lc];
            wkv[lr * 32 + lc + 0] = b.x; wkv[lr * 32 + lc + 1] = b.y;
            wkv[lr * 32 + lc + 2] = b.z; wkv[lr * 32 + lc + 3] = b.w;
            float4 c = *(const float4*)&W_KR[(size_t)(k0 + lr) * 32 + lc];
            wkr[lr * 32 + lc + 0] = c.x; wkr[lr * 32 + lc + 1] = c.y;
            wkr[lr * 32 + lc + 2] = c.z; wkr[lr * 32 + lc + 3] = c.w;
        }
        __syncthreads();
        #pragma unroll 8
        for (int kk = 0; kk < 32; ++kk) {
            float a = hs[t * 33 + kk];
            #pragma unroll
            for (int cc = 0; cc < 4; ++cc) {
                int c = g * 4 + cc;
                acc_q[cc] += a * wq[kk * 32 + c];
                acc_kv[cc] += a * wkv[kk * 32 + c];
                acc_kr[cc] += a * wkr[kk * 32 + c];
            }
        }
    }
    #pragma unroll
    for (int cc = 0; cc < 4; ++cc) {
        int c = g * 4 + cc;
        int idx = (t0 + t) * 32 + c;
        c_q[idx] = acc_q[cc] + b_DQ[c];
        c_kv[idx] = acc_kv[cc] + b_DKV[c];
        k_r[idx] = acc_kr[cc] + b_KR[c];
    }
}

// ============================================================
// Kernel 2: build q, k, v (bf16) in [bh][s][d] layout.
// (unchanged from round 3)
// ============================================================
__global__ __launch_bounds__(256) void build_qkv_kernel(
    const float* __restrict__ c_q, const float* __restrict__ c_kv,
    const float* __restrict__ k_r,
    const float* __restrict__ W_UQ, const float* __restrict__ b_UQ,
    const float* __restrict__ W_UK, const float* __restrict__ b_UK,
    const float* __restrict__ W_UV, const float* __restrict__ b_UV,
    const float* __restrict__ W_QR, const float* __restrict__ b_QR,
    ushort* __restrict__ q_ws, ushort* __restrict__ k_ws, ushort* __restrict__ v_ws)
{
    __shared__ __align__(16) float cb[16 * 96];
    const int tid = threadIdx.x;
    const int t0 = blockIdx.x * 16;

    for (int i = tid; i < 512; i += 256) {
        int tt = i >> 5, c = i & 31;
        cb[tt * 96 + c] = c_q[(t0 + tt) * 32 + c];
        cb[tt * 96 + 32 + c] = c_kv[(t0 + tt) * 32 + c];
        cb[tt * 96 + 64 + c] = k_r[(t0 + tt) * 32 + c];
    }
    __syncthreads();

    for (int i = 0; i < 14; ++i) {
        int e = i * 256 + tid;
        int h = e / 448;
        int r = e - h * 448;

        float acc[16];
        if (r >= 288 && r < 320) {
            #pragma unroll
            for (int tt = 0; tt < 16; ++tt) acc[tt] = cb[tt * 96 + 64 + (r - 288)];
        } else {
            const float* W; const float* bias; int stride, col, coff;
            if (r < 128)      { W = W_UQ; stride = 1024; col = h * 128 + r;        coff = 0;  bias = b_UQ; }
            else if (r < 160) { W = W_QR; stride = 256;  col = h * 32 + (r - 128); coff = 0;  bias = b_QR; }
            else if (r < 288) { W = W_UK; stride = 1024; col = h * 128 + (r - 160);coff = 32; bias = b_UK; }
            else              { W = W_UV; stride = 1024; col = h * 128 + (r - 320);coff = 32; bias = b_UV; }
            float bv = bias[col];
            #pragma unroll
            for (int tt = 0; tt < 16; ++tt) acc[tt] = bv;
            for (int kk = 0; kk < 32; ++kk) {
                float w = W[kk * stride + col];
                #pragma unroll
                for (int tt = 0; tt < 16; ++tt) acc[tt] += cb[tt * 96 + coff + kk] * w;
            }
        }
        #pragma unroll
        for (int tt = 0; tt < 16; ++tt) {
            int tok = t0 + tt;
            int b = tok >> 11, s = tok & 2047;
            int bh = b * NH + h;
            ushort val = f2bf(acc[tt]);
            if (r < 160)      q_ws[((size_t)bh * S_SZ + s) * DQK + r] = val;
            else if (r < 320) k_ws[((size_t)bh * S_SZ + s) * DQK + (r - 160)] = val;
            else              v_ws[((size_t)bh * S_SZ + s) * DK + (r - 320)] = val;
        }
    }
}

// ============================================================
// Kernel 3 (NEW): MFMA flash attention.
// Block = 4 waves, 128 Q rows (32/wave). K-tile = 64 keys.
// mfma_f32_16x16x32_bf16 everywhere; verified layouts:
//   A[m=lane&15][k=quad*8+j], B[k=quad*8+j][n=lane&15],
//   C/D: col=lane&15, row=quad*4+reg.
// Q frags live in registers (loaded once from global).
// V staged transposed in LDS; P round-trips LDS per wave.
// Grid: (S/128, B*H) = (16, 32).
// ============================================================
__global__ __launch_bounds__(256, 2) void attn_mfma_kernel(
    const ushort* __restrict__ q_ws, const ushort* __restrict__ k_ws,
    const ushort* __restrict__ v_ws, ushort* __restrict__ o_ws)
{
    // strides in ushorts; all chosen for 16B alignment + <=2-way banks
    __shared__ __align__(16) ushort Ks[64 * 168];   // [key][d], 21504 B
    __shared__ __align__(16) ushort Vt[128 * 72];   // [d][key] (transposed), 18432 B
    __shared__ __align__(16) ushort Ps[4 * 32 * 72];// per-wave P [row][key], 18432 B

    const int tid = threadIdx.x;
    const int wave = tid >> 6;
    const int lane = tid & 63;
    const int quad = lane >> 4;
    const int l16 = lane & 15;

    const int bh = blockIdx.y;
    const int b = bh >> 3, h = bh & 7;
    const int s0 = blockIdx.x * 128;
    const int qrow_base = s0 + wave * 32;

    // ---- Q fragments: registers, loaded once (A-layout is 16B-contig in global)
    short8 qf[2][5];
    #pragma unroll
    for (int rt = 0; rt < 2; ++rt)
        #pragma unroll
        for (int kb = 0; kb < 5; ++kb) {
            const ushort* p = q_ws + ((size_t)bh * S_SZ + qrow_base + rt * 16 + l16) * DQK
                            + kb * 32 + quad * 8;
            qf[rt][kb] = *(const short8*)p;
        }

    floatx4 oa[2][8];
    #pragma unroll
    for (int rt = 0; rt < 2; ++rt)
        #pragma unroll
        for (int vt = 0; vt < 8; ++vt)
            oa[rt][vt] = (floatx4){0.f, 0.f, 0.f, 0.f};

    float m_run[2][4], l_run[2][4];
    #pragma unroll
    for (int rt = 0; rt < 2; ++rt)
        #pragma unroll
        for (int r = 0; r < 4; ++r) { m_run[rt][r] = -3.0e38f; l_run[rt][r] = 0.f; }

    ushort* psw = Ps + wave * (32 * 72);

    for (int kt = 0; kt < S_SZ / 64; ++kt) {
        const int k0 = kt * 64;
        __syncthreads(); // prior iter's LDS reads done

        // ---- stage K tile: 64 rows x 160 us, as 1280 uint4
        {
            const uint4* kg = (const uint4*)(k_ws + (size_t)bh * S_SZ * DQK + (size_t)k0 * DQK);
            for (int i = tid; i < 1280; i += 256) {
                int row = i / 20, seg = i - row * 20;
                *(uint4*)&Ks[row * 168 + seg * 8] = kg[row * 20 + seg];
            }
        }
        // ---- stage V transposed: Vt[d][key]
        {
            const uint* vg = (const uint*)(v_ws + (size_t)bh * S_SZ * DK + (size_t)k0 * DK);
            uint* vt32 = (uint*)Vt;
            int dp = tid & 63;       // d-pair index (d = 2dp, 2dp+1)
            int kp0 = tid >> 6;      // 0..3
            #pragma unroll
            for (int j = 0; j < 8; ++j) {
                int kp = kp0 + 4 * j;              // key pair (keys 2kp, 2kp+1)
                uint a = vg[(2 * kp) * 64 + dp];
                uint bb = vg[(2 * kp + 1) * 64 + dp];
                vt32[(2 * dp) * 36 + kp]     = (a & 0xffffu) | (bb << 16);
                vt32[(2 * dp + 1) * 36 + kp] = (a >> 16) | (bb & 0xffff0000u);
            }
        }
        __syncthreads();

        // ---- QK^T: scores S[32 rows][64 keys] per wave
        floatx4 sc[2][4];
        #pragma unroll
        for (int ct = 0; ct < 4; ++ct) {
            short8 bf[5];
            #pragma unroll
            for (int kb = 0; kb < 5; ++kb)
                bf[kb] = *(const short8*)&Ks[(ct * 16 + l16) * 168 + kb * 32 + quad * 8];
            #pragma unroll
            for (int rt = 0; rt < 2; ++rt) {
                floatx4 c = (floatx4){0.f, 0.f, 0.f, 0.f};
                #pragma unroll
                for (int kb = 0; kb < 5; ++kb)
                    c = __builtin_amdgcn_mfma_f32_16x16x32_bf16(qf[rt][kb], bf[kb], c, 0, 0, 0);
                sc[rt][ct] = c;
            }
        }

        // ---- online softmax (rows = quad*4 + r within each 16-row tile)
        #pragma unroll
        for (int rt = 0; rt < 2; ++rt) {
            float tmax[4] = {-3.0e38f, -3.0e38f, -3.0e38f, -3.0e38f};
            #pragma unroll
            for (int ct = 0; ct < 4; ++ct)
                #pragma unroll
                for (int r = 0; r < 4; ++r) {
                    sc[rt][ct][r] *= SCALE;
                    tmax[r] = fmaxf(tmax[r], sc[rt][ct][r]);
                }
            #pragma unroll
            for (int r = 0; r < 4; ++r) {
                tmax[r] = fmaxf(tmax[r], __shfl_xor(tmax[r], 1));
                tmax[r] = fmaxf(tmax[r], __shfl_xor(tmax[r], 2));
                tmax[r] = fmaxf(tmax[r], __shfl_xor(tmax[r], 4));
                tmax[r] = fmaxf(tmax[r], __shfl_xor(tmax[r], 8));
            }
            float al[4], mnew[4];
            #pragma unroll
            for (int r = 0; r < 4; ++r) {
                mnew[r] = fmaxf(m_run[rt][r], tmax[r]);
                al[r] = __expf(m_run[rt][r] - mnew[r]);
                m_run[rt][r] = mnew[r];
            }
            float rsum[4] = {0.f, 0.f, 0.f, 0.f};
            #pragma unroll
            for (int ct = 0; ct < 4; ++ct)
                #pragma unroll
                for (int r = 0; r < 4; ++r) {
                    float p = __expf(sc[rt][ct][r] - mnew[r]);
                    rsum[r] += p;
                    psw[(rt * 16 + quad * 4 + r) * 72 + ct * 16 + l16] = f2bf(p);
                }
            #pragma unroll
            for (int r = 0; r < 4; ++r) {
                rsum[r] += __shfl_xor(rsum[r], 1);
                rsum[r] += __shfl_xor(rsum[r], 2);
                rsum[r] += __shfl_xor(rsum[r], 4);
                rsum[r] += __shfl_xor(rsum[r], 8);
                l_run[rt][r] = l_run[rt][r] * al[r] + rsum[r];
            }
            #pragma unroll
            for (int vt = 0; vt < 8; ++vt)
                #pragma unroll
                for (int r = 0; r < 4; ++r)
                    oa[rt][vt][r] *= al[r];
        }

        // ---- PV: O += P @ V  (P read back in A-layout from own wave's LDS;
        //      same-wave DS ops are in-order, no barrier needed)
        #pragma unroll
        for (int kb2 = 0; kb2 < 2; ++kb2) {
            short8 af[2];
            #pragma unroll
            for (int rt = 0; rt < 2; ++rt)
                af[rt] = *(const short8*)&psw[(rt * 16 + l16) * 72 + kb2 * 32 + quad * 8];
            #pragma unroll
            for (int vt = 0; vt < 8; ++vt) {
                short8 vf = *(const short8*)&Vt[(vt * 16 + l16) * 72 + kb2 * 32 + quad * 8];
                #pragma unroll
                for (int rt = 0; rt < 2; ++rt)
                    oa[rt][vt] = __builtin_amdgcn_mfma_f32_16x16x32_bf16(af[rt], vf, oa[rt][vt], 0, 0, 0);
            }
        }
    }

    // ---- epilogue: O /= l, write to o_ws [b,s,h*128+d]
    #pragma unroll
    for (int rt = 0; rt < 2; ++rt)
        #pragma unroll
        for (int r = 0; r < 4; ++r) {
            float inv = 1.0f / l_run[rt][r];
            int srow = qrow_base + rt * 16 + quad * 4 + r;
            ushort* orow = o_ws + (((size_t)b * S_SZ + srow) * NH + h) * DK;
            #pragma unroll
            for (int vt = 0; vt < 8; ++vt)
                orow[vt * 16 + l16] = f2bf(oa[rt][vt][r] * inv);
        }
}

// ============================================================
// Kernel 4: out = o_ws [8192,1024](bf16) @ W_O [1024,1024](fp32) + b_O
// (unchanged from round 3)
// ============================================================
__global__ __launch_bounds__(256) void out_gemm_kernel(
    const ushort* __restrict__ o_ws, const float* __restrict__ W_O,
    const float* __restrict__ b_O, float* __restrict__ out)
{
    __shared__ __align__(16) float Ast[32 * 68];
    __shared__ __align__(16) float Bs[32 * 68];

    const int tid = threadIdx.x;
    const int n0 = blockIdx.x * 64;
    const int m0 = blockIdx.y * 64;
    const int tx = tid & 15, ty = tid >> 4;

    float acc[4][4];
    #pragma unroll
    for (int i = 0; i < 4; ++i)
        #pragma unroll
        for (int j = 0; j < 4; ++j) acc[i][j] = 0.f;

    const uint* Au = (const uint*)o_ws;

    for (int k0 = 0; k0 < DM; k0 += 32) {
        __syncthreads();
        for (int i = tid; i < 1024; i += 256) {
            int r = i >> 4, c2 = i & 15;
            uint v = Au[(size_t)(m0 + r) * (DM / 2) + (k0 >> 1) + c2];
            Ast[(2 * c2) * 68 + r] = bf_lo(v);
            Ast[(2 * c2 + 1) * 68 + r] = bf_hi(v);
        }
        for (int i = tid; i < 512; i += 256) {
            int r = i >> 4, c4 = (i & 15) * 4;
            float4 v = *(const float4*)&W_O[(size_t)(k0 + r) * DM + n0 + c4];
            Bs[r * 68 + c4 + 0] = v.x;
            Bs[r * 68 + c4 + 1] = v.y;
            Bs[r * 68 + c4 + 2] = v.z;
            Bs[r * 68 + c4 + 3] = v.w;
        }
        __syncthreads();
        #pragma unroll 8
        for (int kk = 0; kk < 32; ++kk) {
            float4 a4 = *(const float4*)&Ast[kk * 68 + ty * 4];
            float4 b4 = *(const float4*)&Bs[kk * 68 + tx * 4];
            float av[4] = {a4.x, a4.y, a4.z, a4.w};
            float bv[4] = {b4.x, b4.y, b4.z, b4.w};
            #pragma unroll
            for (int i = 0; i < 4; ++i)
                #pragma unroll
                for (int j = 0; j < 4; ++j) acc[i][j] += av[i] * bv[j];
        }
    }

    float bo[4];
    #pragma unroll
    for (int j = 0; j < 4; ++j) bo[j] = b_O[n0 + tx * 4 + j];
    #pragma unroll
    for (int i = 0; i < 4; ++i) {
        int row = m0 + ty * 4 + i;
        #pragma unroll
        for (int j = 0; j < 4; ++j) {
            out[(size_t)row * DM + n0 + tx * 4 + j] = acc[i][j] + bo[j];
        }
    }
}

// ============================================================
extern "C" void kernel_launch(void* const* d_in, const int* in_sizes, int n_in,
                              void* d_out, int out_size, void* d_ws, size_t ws_size,
                              hipStream_t stream) {
    (void)in_sizes; (void)n_in; (void)out_size; (void)ws_size;

    const float* h_t   = (const float*)d_in[0];
    const float* W_DQ  = (const float*)d_in[1];
    const float* b_DQ  = (const float*)d_in[2];
    const float* W_UQ  = (const float*)d_in[3];
    const float* b_UQ  = (const float*)d_in[4];
    const float* W_DKV = (const float*)d_in[5];
    const float* b_DKV = (const float*)d_in[6];
    const float* W_UK  = (const float*)d_in[7];
    const float* b_UK  = (const float*)d_in[8];
    const float* W_UV  = (const float*)d_in[9];
    const float* b_UV  = (const float*)d_in[10];
    const float* W_QR  = (const float*)d_in[11];
    const float* b_QR  = (const float*)d_in[12];
    const float* W_KR  = (const float*)d_in[13];
    const float* b_KR  = (const float*)d_in[14];
    const float* W_O   = (const float*)d_in[15];
    const float* b_O   = (const float*)d_in[16];

    float* c_q  = (float*)d_ws;
    float* c_kv = c_q + T_TOK * DC;
    float* k_r  = c_kv + T_TOK * DC;
    ushort* q_ws = (ushort*)(k_r + T_TOK * DC);
    ushort* k_ws = q_ws + (size_t)B_SZ * NH * S_SZ * DQK;
    ushort* v_ws = k_ws + (size_t)B_SZ * NH * S_SZ * DQK;
    ushort* o_ws = v_ws + (size_t)B_SZ * NH * S_SZ * DK;

    float* out = (float*)d_out;

    latent_kernel<<<T_TOK / 32, 256, 0, stream>>>(
        h_t, W_DQ, b_DQ, W_DKV, b_DKV, W_KR, b_KR, c_q, c_kv, k_r);

    build_qkv_kernel<<<T_TOK / 16, 256, 0, stream>>>(
        c_q, c_kv, k_r, W_UQ, b_UQ, W_UK, b_UK, W_UV, b_UV, W_QR, b_QR,
        q_ws, k_ws, v_ws);

    attn_mfma_kernel<<<dim3(S_SZ / 128, B_SZ * NH), 256, 0, stream>>>(
        q_ws, k_ws, v_ws, o_ws);

    out_gemm_kernel<<<dim3(DM / 64, T_TOK / 64), 256, 0, stream>>>(
        o_ws, W_O, b_O, out);
}

// Round 5
// 464.078 us; speedup vs baseline: 5.7620x; 1.3778x over previous
//
#include <hip/hip_runtime.h>
#include <hip/hip_bf16.h>

// ---- problem constants ----
#define B_SZ 4
#define S_SZ 2048
#define DM   1024
#define NH   8
#define DK   128
#define DC   32
#define DHR  32
#define DQK  160            // DK + DHR
#define T_TOK (B_SZ * S_SZ) // 8192
#define SCALE 0.07905694150420949f // 1/sqrt(160)

typedef unsigned int uint;
typedef unsigned short ushort;
typedef __attribute__((ext_vector_type(8))) short short8;
typedef __attribute__((ext_vector_type(4))) float floatx4;

__device__ __forceinline__ float bf_lo(uint u) { return __uint_as_float(u << 16); }
__device__ __forceinline__ float bf_hi(uint u) { return __uint_as_float(u & 0xffff0000u); }
__device__ __forceinline__ ushort f2bf(float f) {
    uint u = __float_as_uint(f);
    uint r = u + 0x7fffu + ((u >> 16) & 1u);
    return (ushort)(r >> 16);
}

// async global->LDS, 16B per lane; lds dest = wave-uniform base + lane*16
__device__ __forceinline__ void glds16(const ushort* g, ushort* l) {
    __builtin_amdgcn_global_load_lds(
        (const __attribute__((address_space(1))) uint*)g,
        (__attribute__((address_space(3))) uint*)l, 16, 0, 0);
}

// ============================================================
// Kernel 1: c_q, c_kv, k_r  = h_t @ {W_DQ, W_DKV, W_KR} + bias
// (unchanged)
// ============================================================
__global__ __launch_bounds__(256) void latent_kernel(
    const float* __restrict__ h_t,
    const float* __restrict__ W_DQ, const float* __restrict__ b_DQ,
    const float* __restrict__ W_DKV, const float* __restrict__ b_DKV,
    const float* __restrict__ W_KR, const float* __restrict__ b_KR,
    float* __restrict__ c_q, float* __restrict__ c_kv, float* __restrict__ k_r)
{
    __shared__ __align__(16) float hs[32 * 33];
    __shared__ __align__(16) float wq[32 * 32];
    __shared__ __align__(16) float wkv[32 * 32];
    __shared__ __align__(16) float wkr[32 * 32];

    const int tid = threadIdx.x;
    const int t0 = blockIdx.x * 32;
    const int t = tid & 31;
    const int g = tid >> 5;

    float acc_q[4] = {0.f, 0.f, 0.f, 0.f};
    float acc_kv[4] = {0.f, 0.f, 0.f, 0.f};
    float acc_kr[4] = {0.f, 0.f, 0.f, 0.f};

    const int lr = tid >> 3;
    const int lc = (tid & 7) * 4;

    for (int k0 = 0; k0 < DM; k0 += 32) {
        __syncthreads();
        {
            float4 v = *(const float4*)&h_t[(size_t)(t0 + lr) * DM + k0 + lc];
            hs[lr * 33 + lc + 0] = v.x;
            hs[lr * 33 + lc + 1] = v.y;
            hs[lr * 33 + lc + 2] = v.z;
            hs[lr * 33 + lc + 3] = v.w;
        }
        {
            float4 a = *(const float4*)&W_DQ[(size_t)(k0 + lr) * 32 + lc];
            wq[lr * 32 + lc + 0] = a.x; wq[lr * 32 + lc + 1] = a.y;
            wq[lr * 32 + lc + 2] = a.z; wq[lr * 32 + lc + 3] = a.w;
            float4 b = *(const float4*)&W_DKV[(size_t)(k0 + lr) * 32 + lc];
            wkv[lr * 32 + lc + 0] = b.x; wkv[lr * 32 + lc + 1] = b.y;
            wkv[lr * 32 + lc + 2] = b.z; wkv[lr * 32 + lc + 3] = b.w;
            float4 c = *(const float4*)&W_KR[(size_t)(k0 + lr) * 32 + lc];
            wkr[lr * 32 + lc + 0] = c.x; wkr[lr * 32 + lc + 1] = c.y;
            wkr[lr * 32 + lc + 2] = c.z; wkr[lr * 32 + lc + 3] = c.w;
        }
        __syncthreads();
        #pragma unroll 8
        for (int kk = 0; kk < 32; ++kk) {
            float a = hs[t * 33 + kk];
            #pragma unroll
            for (int cc = 0; cc < 4; ++cc) {
                int c = g * 4 + cc;
                acc_q[cc] += a * wq[kk * 32 + c];
                acc_kv[cc] += a * wkv[kk * 32 + c];
                acc_kr[cc] += a * wkr[kk * 32 + c];
            }
        }
    }
    #pragma unroll
    for (int cc = 0; cc < 4; ++cc) {
        int c = g * 4 + cc;
        int idx = (t0 + t) * 32 + c;
        c_q[idx] = acc_q[cc] + b_DQ[c];
        c_kv[idx] = acc_kv[cc] + b_DKV[c];
        k_r[idx] = acc_kr[cc] + b_KR[c];
    }
}

// ============================================================
// Kernel 2: build q, k, v (bf16) in [bh][s][d] layout. (unchanged)
// ============================================================
__global__ __launch_bounds__(256) void build_qkv_kernel(
    const float* __restrict__ c_q, const float* __restrict__ c_kv,
    const float* __restrict__ k_r,
    const float* __restrict__ W_UQ, const float* __restrict__ b_UQ,
    const float* __restrict__ W_UK, const float* __restrict__ b_UK,
    const float* __restrict__ W_UV, const float* __restrict__ b_UV,
    const float* __restrict__ W_QR, const float* __restrict__ b_QR,
    ushort* __restrict__ q_ws, ushort* __restrict__ k_ws, ushort* __restrict__ v_ws)
{
    __shared__ __align__(16) float cb[16 * 96];
    const int tid = threadIdx.x;
    const int t0 = blockIdx.x * 16;

    for (int i = tid; i < 512; i += 256) {
        int tt = i >> 5, c = i & 31;
        cb[tt * 96 + c] = c_q[(t0 + tt) * 32 + c];
        cb[tt * 96 + 32 + c] = c_kv[(t0 + tt) * 32 + c];
        cb[tt * 96 + 64 + c] = k_r[(t0 + tt) * 32 + c];
    }
    __syncthreads();

    for (int i = 0; i < 14; ++i) {
        int e = i * 256 + tid;
        int h = e / 448;
        int r = e - h * 448;

        float acc[16];
        if (r >= 288 && r < 320) {
            #pragma unroll
            for (int tt = 0; tt < 16; ++tt) acc[tt] = cb[tt * 96 + 64 + (r - 288)];
        } else {
            const float* W; const float* bias; int stride, col, coff;
            if (r < 128)      { W = W_UQ; stride = 1024; col = h * 128 + r;        coff = 0;  bias = b_UQ; }
            else if (r < 160) { W = W_QR; stride = 256;  col = h * 32 + (r - 128); coff = 0;  bias = b_QR; }
            else if (r < 288) { W = W_UK; stride = 1024; col = h * 128 + (r - 160);coff = 32; bias = b_UK; }
            else              { W = W_UV; stride = 1024; col = h * 128 + (r - 320);coff = 32; bias = b_UV; }
            float bv = bias[col];
            #pragma unroll
            for (int tt = 0; tt < 16; ++tt) acc[tt] = bv;
            for (int kk = 0; kk < 32; ++kk) {
                float w = W[kk * stride + col];
                #pragma unroll
                for (int tt = 0; tt < 16; ++tt) acc[tt] += cb[tt * 96 + coff + kk] * w;
            }
        }
        #pragma unroll
        for (int tt = 0; tt < 16; ++tt) {
            int tok = t0 + tt;
            int b = tok >> 11, s = tok & 2047;
            int bh = b * NH + h;
            ushort val = f2bf(acc[tt]);
            if (r < 160)      q_ws[((size_t)bh * S_SZ + s) * DQK + r] = val;
            else if (r < 320) k_ws[((size_t)bh * S_SZ + s) * DQK + (r - 160)] = val;
            else              v_ws[((size_t)bh * S_SZ + s) * DK + (r - 320)] = val;
        }
    }
}

// ============================================================
// Kernel 3: MFMA flash attention. (unchanged from round 4)
// ============================================================
__global__ __launch_bounds__(256, 2) void attn_mfma_kernel(
    const ushort* __restrict__ q_ws, const ushort* __restrict__ k_ws,
    const ushort* __restrict__ v_ws, ushort* __restrict__ o_ws)
{
    __shared__ __align__(16) ushort Ks[64 * 168];
    __shared__ __align__(16) ushort Vt[128 * 72];
    __shared__ __align__(16) ushort Ps[4 * 32 * 72];

    const int tid = threadIdx.x;
    const int wave = tid >> 6;
    const int lane = tid & 63;
    const int quad = lane >> 4;
    const int l16 = lane & 15;

    const int bh = blockIdx.y;
    const int b = bh >> 3, h = bh & 7;
    const int s0 = blockIdx.x * 128;
    const int qrow_base = s0 + wave * 32;

    short8 qf[2][5];
    #pragma unroll
    for (int rt = 0; rt < 2; ++rt)
        #pragma unroll
        for (int kb = 0; kb < 5; ++kb) {
            const ushort* p = q_ws + ((size_t)bh * S_SZ + qrow_base + rt * 16 + l16) * DQK
                            + kb * 32 + quad * 8;
            qf[rt][kb] = *(const short8*)p;
        }

    floatx4 oa[2][8];
    #pragma unroll
    for (int rt = 0; rt < 2; ++rt)
        #pragma unroll
        for (int vt = 0; vt < 8; ++vt)
            oa[rt][vt] = (floatx4){0.f, 0.f, 0.f, 0.f};

    float m_run[2][4], l_run[2][4];
    #pragma unroll
    for (int rt = 0; rt < 2; ++rt)
        #pragma unroll
        for (int r = 0; r < 4; ++r) { m_run[rt][r] = -3.0e38f; l_run[rt][r] = 0.f; }

    ushort* psw = Ps + wave * (32 * 72);

    for (int kt = 0; kt < S_SZ / 64; ++kt) {
        const int k0 = kt * 64;
        __syncthreads();

        {
            const uint4* kg = (const uint4*)(k_ws + (size_t)bh * S_SZ * DQK + (size_t)k0 * DQK);
            for (int i = tid; i < 1280; i += 256) {
                int row = i / 20, seg = i - row * 20;
                *(uint4*)&Ks[row * 168 + seg * 8] = kg[row * 20 + seg];
            }
        }
        {
            const uint* vg = (const uint*)(v_ws + (size_t)bh * S_SZ * DK + (size_t)k0 * DK);
            uint* vt32 = (uint*)Vt;
            int dp = tid & 63;
            int kp0 = tid >> 6;
            #pragma unroll
            for (int j = 0; j < 8; ++j) {
                int kp = kp0 + 4 * j;
                uint a = vg[(2 * kp) * 64 + dp];
                uint bb = vg[(2 * kp + 1) * 64 + dp];
                vt32[(2 * dp) * 36 + kp]     = (a & 0xffffu) | (bb << 16);
                vt32[(2 * dp + 1) * 36 + kp] = (a >> 16) | (bb & 0xffff0000u);
            }
        }
        __syncthreads();

        floatx4 sc[2][4];
        #pragma unroll
        for (int ct = 0; ct < 4; ++ct) {
            short8 bf[5];
            #pragma unroll
            for (int kb = 0; kb < 5; ++kb)
                bf[kb] = *(const short8*)&Ks[(ct * 16 + l16) * 168 + kb * 32 + quad * 8];
            #pragma unroll
            for (int rt = 0; rt < 2; ++rt) {
                floatx4 c = (floatx4){0.f, 0.f, 0.f, 0.f};
                #pragma unroll
                for (int kb = 0; kb < 5; ++kb)
                    c = __builtin_amdgcn_mfma_f32_16x16x32_bf16(qf[rt][kb], bf[kb], c, 0, 0, 0);
                sc[rt][ct] = c;
            }
        }

        #pragma unroll
        for (int rt = 0; rt < 2; ++rt) {
            float tmax[4] = {-3.0e38f, -3.0e38f, -3.0e38f, -3.0e38f};
            #pragma unroll
            for (int ct = 0; ct < 4; ++ct)
                #pragma unroll
                for (int r = 0; r < 4; ++r) {
                    sc[rt][ct][r] *= SCALE;
                    tmax[r] = fmaxf(tmax[r], sc[rt][ct][r]);
                }
            #pragma unroll
            for (int r = 0; r < 4; ++r) {
                tmax[r] = fmaxf(tmax[r], __shfl_xor(tmax[r], 1));
                tmax[r] = fmaxf(tmax[r], __shfl_xor(tmax[r], 2));
                tmax[r] = fmaxf(tmax[r], __shfl_xor(tmax[r], 4));
                tmax[r] = fmaxf(tmax[r], __shfl_xor(tmax[r], 8));
            }
            float al[4], mnew[4];
            #pragma unroll
            for (int r = 0; r < 4; ++r) {
                mnew[r] = fmaxf(m_run[rt][r], tmax[r]);
                al[r] = __expf(m_run[rt][r] - mnew[r]);
                m_run[rt][r] = mnew[r];
            }
            float rsum[4] = {0.f, 0.f, 0.f, 0.f};
            #pragma unroll
            for (int ct = 0; ct < 4; ++ct)
                #pragma unroll
                for (int r = 0; r < 4; ++r) {
                    float p = __expf(sc[rt][ct][r] - mnew[r]);
                    rsum[r] += p;
                    psw[(rt * 16 + quad * 4 + r) * 72 + ct * 16 + l16] = f2bf(p);
                }
            #pragma unroll
            for (int r = 0; r < 4; ++r) {
                rsum[r] += __shfl_xor(rsum[r], 1);
                rsum[r] += __shfl_xor(rsum[r], 2);
                rsum[r] += __shfl_xor(rsum[r], 4);
                rsum[r] += __shfl_xor(rsum[r], 8);
                l_run[rt][r] = l_run[rt][r] * al[r] + rsum[r];
            }
            #pragma unroll
            for (int vt = 0; vt < 8; ++vt)
                #pragma unroll
                for (int r = 0; r < 4; ++r)
                    oa[rt][vt][r] *= al[r];
        }

        #pragma unroll
        for (int kb2 = 0; kb2 < 2; ++kb2) {
            short8 af[2];
            #pragma unroll
            for (int rt = 0; rt < 2; ++rt)
                af[rt] = *(const short8*)&psw[(rt * 16 + l16) * 72 + kb2 * 32 + quad * 8];
            #pragma unroll
            for (int vt = 0; vt < 8; ++vt) {
                short8 vf = *(const short8*)&Vt[(vt * 16 + l16) * 72 + kb2 * 32 + quad * 8];
                #pragma unroll
                for (int rt = 0; rt < 2; ++rt)
                    oa[rt][vt] = __builtin_amdgcn_mfma_f32_16x16x32_bf16(af[rt], vf, oa[rt][vt], 0, 0, 0);
            }
        }
    }

    #pragma unroll
    for (int rt = 0; rt < 2; ++rt)
        #pragma unroll
        for (int r = 0; r < 4; ++r) {
            float inv = 1.0f / l_run[rt][r];
            int srow = qrow_base + rt * 16 + quad * 4 + r;
            ushort* orow = o_ws + (((size_t)b * S_SZ + srow) * NH + h) * DK;
            #pragma unroll
            for (int vt = 0; vt < 8; ++vt)
                orow[vt * 16 + l16] = f2bf(oa[rt][vt][r] * inv);
        }
}

// ============================================================
// Kernel 4a (NEW): W_O [1024 k][1024 n] fp32 -> W_O^T bf16 [n][k]
// 32x32 tiles, 256 thr. Grid (32, 32).
// ============================================================
__global__ __launch_bounds__(256) void transpose_wo_kernel(
    const float* __restrict__ W_O, ushort* __restrict__ wot)
{
    __shared__ float t[32][33];
    const int tx = threadIdx.x & 31, ty = threadIdx.x >> 5; // ty 0..7
    const int n0 = blockIdx.x * 32, k0 = blockIdx.y * 32;
    #pragma unroll
    for (int j = 0; j < 32; j += 8)
        t[ty + j][tx] = W_O[(size_t)(k0 + ty + j) * DM + n0 + tx];
    __syncthreads();
    #pragma unroll
    for (int j = 0; j < 32; j += 8)
        wot[(size_t)(n0 + ty + j) * DM + k0 + tx] = f2bf(t[tx][ty + j]);
}

// ============================================================
// Kernel 4b (NEW): out = o_ws [8192,1024](bf16) @ wot^T + b_O (fp32 out)
// m97-style: 128x128 tile, BK=32, 4 waves x (64x64), 16x16x32 MFMA,
// global_load_lds width-16 staging into unpadded [row][32] LDS.
// Grid: (1024/128, 8192/128) = (8, 64).
// ============================================================
__global__ __launch_bounds__(256) void out_gemm_mfma_kernel(
    const ushort* __restrict__ A,    // o_ws [8192][1024] bf16
    const ushort* __restrict__ BT,   // wot  [1024 n][1024 k] bf16
    const float* __restrict__ b_O, float* __restrict__ out)
{
    __shared__ __align__(16) ushort As[128 * 32]; // [row][k] unpadded (glds contract)
    __shared__ __align__(16) ushort Bs[128 * 32]; // [n][k]   unpadded

    const int tid = threadIdx.x;
    const int wave = tid >> 6;
    const int lane = tid & 63;
    const int quad = lane >> 4;
    const int l16 = lane & 15;
    const int wr = wave >> 1, wc = wave & 1;

    const int n0 = blockIdx.x * 128;
    const int m0 = blockIdx.y * 128;

    const int lrow = lane >> 2;         // 0..15
    const int lseg = (lane & 3) * 8;    // ushort offset 0,8,16,24

    floatx4 acc[4][4];
    #pragma unroll
    for (int mt = 0; mt < 4; ++mt)
        #pragma unroll
        for (int nt = 0; nt < 4; ++nt)
            acc[mt][nt] = (floatx4){0.f, 0.f, 0.f, 0.f};

    for (int k0 = 0; k0 < DM; k0 += 32) {
        __syncthreads(); // prior iter's ds_reads done before overwrite
        // A: wave covers rows wave*32 .. +31 (two 16-row glds)
        {
            const ushort* g0 = A + (size_t)(m0 + wave * 32 + lrow) * DM + k0 + lseg;
            glds16(g0, &As[(wave * 32) * 32]);
            const ushort* g1 = A + (size_t)(m0 + wave * 32 + 16 + lrow) * DM + k0 + lseg;
            glds16(g1, &As[(wave * 32 + 16) * 32]);
        }
        // B: wave covers n rows wave*32 .. +31
        {
            const ushort* g0 = BT + (size_t)(n0 + wave * 32 + lrow) * DM + k0 + lseg;
            glds16(g0, &Bs[(wave * 32) * 32]);
            const ushort* g1 = BT + (size_t)(n0 + wave * 32 + 16 + lrow) * DM + k0 + lseg;
            glds16(g1, &Bs[(wave * 32 + 16) * 32]);
        }
        __syncthreads(); // drains vmcnt (compiler) + barrier

        short8 af[4], bf[4];
        #pragma unroll
        for (int mt = 0; mt < 4; ++mt)
            af[mt] = *(const short8*)&As[(wr * 64 + mt * 16 + l16) * 32 + quad * 8];
        #pragma unroll
        for (int nt = 0; nt < 4; ++nt)
            bf[nt] = *(const short8*)&Bs[(wc * 64 + nt * 16 + l16) * 32 + quad * 8];
        #pragma unroll
        for (int mt = 0; mt < 4; ++mt)
            #pragma unroll
            for (int nt = 0; nt < 4; ++nt)
                acc[mt][nt] = __builtin_amdgcn_mfma_f32_16x16x32_bf16(af[mt], bf[nt], acc[mt][nt], 0, 0, 0);
    }

    float bo[4];
    #pragma unroll
    for (int nt = 0; nt < 4; ++nt) bo[nt] = b_O[n0 + wc * 64 + nt * 16 + l16];

    #pragma unroll
    for (int mt = 0; mt < 4; ++mt) {
        #pragma unroll
        for (int r = 0; r < 4; ++r) {
            int row = m0 + wr * 64 + mt * 16 + quad * 4 + r;
            float* orow = out + (size_t)row * DM + n0 + wc * 64;
            #pragma unroll
            for (int nt = 0; nt < 4; ++nt)
                orow[nt * 16 + l16] = acc[mt][nt][r] + bo[nt];
        }
    }
}

// ============================================================
extern "C" void kernel_launch(void* const* d_in, const int* in_sizes, int n_in,
                              void* d_out, int out_size, void* d_ws, size_t ws_size,
                              hipStream_t stream) {
    (void)in_sizes; (void)n_in; (void)out_size; (void)ws_size;

    const float* h_t   = (const float*)d_in[0];
    const float* W_DQ  = (const float*)d_in[1];
    const float* b_DQ  = (const float*)d_in[2];
    const float* W_UQ  = (const float*)d_in[3];
    const float* b_UQ  = (const float*)d_in[4];
    const float* W_DKV = (const float*)d_in[5];
    const float* b_DKV = (const float*)d_in[6];
    const float* W_UK  = (const float*)d_in[7];
    const float* b_UK  = (const float*)d_in[8];
    const float* W_UV  = (const float*)d_in[9];
    const float* b_UV  = (const float*)d_in[10];
    const float* W_QR  = (const float*)d_in[11];
    const float* b_QR  = (const float*)d_in[12];
    const float* W_KR  = (const float*)d_in[13];
    const float* b_KR  = (const float*)d_in[14];
    const float* W_O   = (const float*)d_in[15];
    const float* b_O   = (const float*)d_in[16];

    // workspace carve: 3MB fp32 latents + 21+21+16.8+16.8 MB bf16 + 2MB wot
    float* c_q  = (float*)d_ws;
    float* c_kv = c_q + T_TOK * DC;
    float* k_r  = c_kv + T_TOK * DC;
    ushort* q_ws = (ushort*)(k_r + T_TOK * DC);
    ushort* k_ws = q_ws + (size_t)B_SZ * NH * S_SZ * DQK;
    ushort* v_ws = k_ws + (size_t)B_SZ * NH * S_SZ * DQK;
    ushort* o_ws = v_ws + (size_t)B_SZ * NH * S_SZ * DK;
    ushort* wot  = o_ws + (size_t)T_TOK * DM;

    float* out = (float*)d_out;

    latent_kernel<<<T_TOK / 32, 256, 0, stream>>>(
        h_t, W_DQ, b_DQ, W_DKV, b_DKV, W_KR, b_KR, c_q, c_kv, k_r);

    transpose_wo_kernel<<<dim3(32, 32), 256, 0, stream>>>(W_O, wot);

    build_qkv_kernel<<<T_TOK / 16, 256, 0, stream>>>(
        c_q, c_kv, k_r, W_UQ, b_UQ, W_UK, b_UK, W_UV, b_UV, W_QR, b_QR,
        q_ws, k_ws, v_ws);

    attn_mfma_kernel<<<dim3(S_SZ / 128, B_SZ * NH), 256, 0, stream>>>(
        q_ws, k_ws, v_ws, o_ws);

    out_gemm_mfma_kernel<<<dim3(DM / 128, T_TOK / 128), 256, 0, stream>>>(
        o_ws, wot, b_O, out);
}

// Round 6
// 463.915 us; speedup vs baseline: 5.7641x; 1.0004x over previous
//
#include <hip/hip_runtime.h>
#include <hip/hip_bf16.h>

// ---- problem constants ----
#define B_SZ 4
#define S_SZ 2048
#define DM   1024
#define NH   8
#define DK   128
#define DC   32
#define DHR  32
#define DQK  160            // DK + DHR
#define T_TOK (B_SZ * S_SZ) // 8192
#define SCALE 0.07905694150420949f // 1/sqrt(160)

typedef unsigned int uint;
typedef unsigned short ushort;
typedef __attribute__((ext_vector_type(8))) short short8;
typedef __attribute__((ext_vector_type(4))) float floatx4;

__device__ __forceinline__ float bf_lo(uint u) { return __uint_as_float(u << 16); }
__device__ __forceinline__ float bf_hi(uint u) { return __uint_as_float(u & 0xffff0000u); }
__device__ __forceinline__ ushort f2bf(float f) {
    uint u = __float_as_uint(f);
    uint r = u + 0x7fffu + ((u >> 16) & 1u);
    return (ushort)(r >> 16);
}
__device__ __forceinline__ uint packbf(float x, float y) {
    return (uint)f2bf(x) | ((uint)f2bf(y) << 16);
}

// async global->LDS, 16B per lane; lds dest = wave-uniform base + lane*16
__device__ __forceinline__ void glds16(const ushort* g, ushort* l) {
    __builtin_amdgcn_global_load_lds(
        (const __attribute__((address_space(1))) uint*)g,
        (__attribute__((address_space(3))) uint*)l, 16, 0, 0);
}

// ============================================================
// Kernel 1: c_q, c_kv, k_r  = h_t @ {W_DQ, W_DKV, W_KR} + bias
// (unchanged)
// ============================================================
__global__ __launch_bounds__(256) void latent_kernel(
    const float* __restrict__ h_t,
    const float* __restrict__ W_DQ, const float* __restrict__ b_DQ,
    const float* __restrict__ W_DKV, const float* __restrict__ b_DKV,
    const float* __restrict__ W_KR, const float* __restrict__ b_KR,
    float* __restrict__ c_q, float* __restrict__ c_kv, float* __restrict__ k_r)
{
    __shared__ __align__(16) float hs[32 * 33];
    __shared__ __align__(16) float wq[32 * 32];
    __shared__ __align__(16) float wkv[32 * 32];
    __shared__ __align__(16) float wkr[32 * 32];

    const int tid = threadIdx.x;
    const int t0 = blockIdx.x * 32;
    const int t = tid & 31;
    const int g = tid >> 5;

    float acc_q[4] = {0.f, 0.f, 0.f, 0.f};
    float acc_kv[4] = {0.f, 0.f, 0.f, 0.f};
    float acc_kr[4] = {0.f, 0.f, 0.f, 0.f};

    const int lr = tid >> 3;
    const int lc = (tid & 7) * 4;

    for (int k0 = 0; k0 < DM; k0 += 32) {
        __syncthreads();
        {
            float4 v = *(const float4*)&h_t[(size_t)(t0 + lr) * DM + k0 + lc];
            hs[lr * 33 + lc + 0] = v.x;
            hs[lr * 33 + lc + 1] = v.y;
            hs[lr * 33 + lc + 2] = v.z;
            hs[lr * 33 + lc + 3] = v.w;
        }
        {
            float4 a = *(const float4*)&W_DQ[(size_t)(k0 + lr) * 32 + lc];
            wq[lr * 32 + lc + 0] = a.x; wq[lr * 32 + lc + 1] = a.y;
            wq[lr * 32 + lc + 2] = a.z; wq[lr * 32 + lc + 3] = a.w;
            float4 b = *(const float4*)&W_DKV[(size_t)(k0 + lr) * 32 + lc];
            wkv[lr * 32 + lc + 0] = b.x; wkv[lr * 32 + lc + 1] = b.y;
            wkv[lr * 32 + lc + 2] = b.z; wkv[lr * 32 + lc + 3] = b.w;
            float4 c = *(const float4*)&W_KR[(size_t)(k0 + lr) * 32 + lc];
            wkr[lr * 32 + lc + 0] = c.x; wkr[lr * 32 + lc + 1] = c.y;
            wkr[lr * 32 + lc + 2] = c.z; wkr[lr * 32 + lc + 3] = c.w;
        }
        __syncthreads();
        #pragma unroll 8
        for (int kk = 0; kk < 32; ++kk) {
            float a = hs[t * 33 + kk];
            #pragma unroll
            for (int cc = 0; cc < 4; ++cc) {
                int c = g * 4 + cc;
                acc_q[cc] += a * wq[kk * 32 + c];
                acc_kv[cc] += a * wkv[kk * 32 + c];
                acc_kr[cc] += a * wkr[kk * 32 + c];
            }
        }
    }
    #pragma unroll
    for (int cc = 0; cc < 4; ++cc) {
        int c = g * 4 + cc;
        int idx = (t0 + t) * 32 + c;
        c_q[idx] = acc_q[cc] + b_DQ[c];
        c_kv[idx] = acc_kv[cc] + b_DKV[c];
        k_r[idx] = acc_kr[cc] + b_KR[c];
    }
}

// ============================================================
// Kernel 2: build q, k, v (bf16) in [bh][s][d] layout. (unchanged)
// ============================================================
__global__ __launch_bounds__(256) void build_qkv_kernel(
    const float* __restrict__ c_q, const float* __restrict__ c_kv,
    const float* __restrict__ k_r,
    const float* __restrict__ W_UQ, const float* __restrict__ b_UQ,
    const float* __restrict__ W_UK, const float* __restrict__ b_UK,
    const float* __restrict__ W_UV, const float* __restrict__ b_UV,
    const float* __restrict__ W_QR, const float* __restrict__ b_QR,
    ushort* __restrict__ q_ws, ushort* __restrict__ k_ws, ushort* __restrict__ v_ws)
{
    __shared__ __align__(16) float cb[16 * 96];
    const int tid = threadIdx.x;
    const int t0 = blockIdx.x * 16;

    for (int i = tid; i < 512; i += 256) {
        int tt = i >> 5, c = i & 31;
        cb[tt * 96 + c] = c_q[(t0 + tt) * 32 + c];
        cb[tt * 96 + 32 + c] = c_kv[(t0 + tt) * 32 + c];
        cb[tt * 96 + 64 + c] = k_r[(t0 + tt) * 32 + c];
    }
    __syncthreads();

    for (int i = 0; i < 14; ++i) {
        int e = i * 256 + tid;
        int h = e / 448;
        int r = e - h * 448;

        float acc[16];
        if (r >= 288 && r < 320) {
            #pragma unroll
            for (int tt = 0; tt < 16; ++tt) acc[tt] = cb[tt * 96 + 64 + (r - 288)];
        } else {
            const float* W; const float* bias; int stride, col, coff;
            if (r < 128)      { W = W_UQ; stride = 1024; col = h * 128 + r;        coff = 0;  bias = b_UQ; }
            else if (r < 160) { W = W_QR; stride = 256;  col = h * 32 + (r - 128); coff = 0;  bias = b_QR; }
            else if (r < 288) { W = W_UK; stride = 1024; col = h * 128 + (r - 160);coff = 32; bias = b_UK; }
            else              { W = W_UV; stride = 1024; col = h * 128 + (r - 320);coff = 32; bias = b_UV; }
            float bv = bias[col];
            #pragma unroll
            for (int tt = 0; tt < 16; ++tt) acc[tt] = bv;
            for (int kk = 0; kk < 32; ++kk) {
                float w = W[kk * stride + col];
                #pragma unroll
                for (int tt = 0; tt < 16; ++tt) acc[tt] += cb[tt * 96 + coff + kk] * w;
            }
        }
        #pragma unroll
        for (int tt = 0; tt < 16; ++tt) {
            int tok = t0 + tt;
            int b = tok >> 11, s = tok & 2047;
            int bh = b * NH + h;
            ushort val = f2bf(acc[tt]);
            if (r < 160)      q_ws[((size_t)bh * S_SZ + s) * DQK + r] = val;
            else if (r < 320) k_ws[((size_t)bh * S_SZ + s) * DQK + (r - 160)] = val;
            else              v_ws[((size_t)bh * S_SZ + s) * DK + (r - 320)] = val;
        }
    }
}

// ============================================================
// Kernel 3 (REWRITE): transposed-score MFMA flash attention.
// Sc^T = K·Q^T (Q regs serve as B-frag unchanged); O^T = V^T·P^T.
// Key permutation in K staging makes P^T a pure register repack:
//   score slot (ct, quad', r) holds physical key
//   p = (r>>1)*32 + quad'*8 + ct*2 + (r&1)
// so PV B-frag dword j2 (kb2) = packbf(p[ct=j2][2*kb2], p[ct=j2][2*kb2+1]).
// Softmax is per-lane scalar (reduce over quads: shfl_xor 16,32).
// LDS = Ks + Vt only (39936 B) -> 3 blocks/CU at VGPR<=170.
// Grid: (S/128, B*H) = (16, 32).
// ============================================================
__global__ __launch_bounds__(256, 3) void attn_mfma_kernel(
    const ushort* __restrict__ q_ws, const ushort* __restrict__ k_ws,
    const ushort* __restrict__ v_ws, ushort* __restrict__ o_ws)
{
    __shared__ __align__(16) ushort SH[64 * 168 + 128 * 72]; // 39936 B
    ushort* const Ks = SH;             // [score-row][d], stride 168
    ushort* const Vt = SH + 64 * 168;  // [d][key], stride 72

    const int tid = threadIdx.x;
    const int wave = tid >> 6;
    const int lane = tid & 63;
    const int quad = lane >> 4;
    const int l16 = lane & 15;

    const int bh = blockIdx.y;
    const int b = bh >> 3, h = bh & 7;
    const int s0 = blockIdx.x * 128;
    const int qrow_base = s0 + wave * 32;

    // Q fragments (same registers serve as B-operand of the swapped MFMA)
    short8 qf[2][5];
    #pragma unroll
    for (int rt = 0; rt < 2; ++rt)
        #pragma unroll
        for (int kb = 0; kb < 5; ++kb) {
            const ushort* p = q_ws + ((size_t)bh * S_SZ + qrow_base + rt * 16 + l16) * DQK
                            + kb * 32 + quad * 8;
            qf[rt][kb] = *(const short8*)p;
        }

    floatx4 oa[2][8];   // O^T: col(l16)=qrow, row(quad*4+r)=d
    #pragma unroll
    for (int rt = 0; rt < 2; ++rt)
        #pragma unroll
        for (int vt = 0; vt < 8; ++vt)
            oa[rt][vt] = (floatx4){0.f, 0.f, 0.f, 0.f};

    float m_run[2] = {-3.0e38f, -3.0e38f};
    float l_run[2] = {0.f, 0.f};

    for (int kt = 0; kt < S_SZ / 64; ++kt) {
        const int k0 = kt * 64;
        __syncthreads(); // all waves done reading prior tile

        // ---- stage K with score-slot permutation: Ks row sr <- phys key p(sr)
        {
            const uint4* kg = (const uint4*)(k_ws + (size_t)bh * S_SZ * DQK + (size_t)k0 * DQK);
            for (int i = tid; i < 1280; i += 256) {
                int row = i / 20, seg = i - row * 20;
                int prow = ((row & 2) >> 1) * 32 + ((row >> 2) & 3) * 8
                         + ((row >> 4) << 1) + (row & 1);
                *(uint4*)&Ks[row * 168 + seg * 8] = kg[prow * 20 + seg];
            }
        }
        // ---- stage V transposed (b128 row-segment writes, <=2-way banks)
        {
            const uint* vg = (const uint*)(v_ws + (size_t)bh * S_SZ * DK + (size_t)k0 * DK);
            uint* vt32 = (uint*)Vt;
            const int dp = tid & 63;   // d-pair: rows 2dp, 2dp+1
            const int kq0 = tid >> 6;  // key-quad base
            #pragma unroll
            for (int j = 0; j < 2; ++j) {
                int kq = kq0 + 4 * j;
                uint lo[4], hi[4];
                #pragma unroll
                for (int c = 0; c < 4; ++c) {
                    int kp = kq * 4 + c;
                    uint a  = vg[(2 * kp) * 64 + dp];
                    uint bb = vg[(2 * kp + 1) * 64 + dp];
                    lo[c] = (a & 0xffffu) | (bb << 16);
                    hi[c] = (a >> 16) | (bb & 0xffff0000u);
                }
                *(uint4*)&vt32[(2 * dp) * 36 + kq * 4]     = make_uint4(lo[0], lo[1], lo[2], lo[3]);
                *(uint4*)&vt32[(2 * dp + 1) * 36 + kq * 4] = make_uint4(hi[0], hi[1], hi[2], hi[3]);
            }
        }
        __syncthreads();

        // ---- Sc^T = K·Q^T : D[m=key(slot)][n=qrow]
        floatx4 sc[2][4];
        #pragma unroll
        for (int ct = 0; ct < 4; ++ct) {
            sc[0][ct] = (floatx4){0.f, 0.f, 0.f, 0.f};
            sc[1][ct] = (floatx4){0.f, 0.f, 0.f, 0.f};
            #pragma unroll
            for (int kb = 0; kb < 5; ++kb) {
                short8 kf = *(const short8*)&Ks[(ct * 16 + l16) * 168 + kb * 32 + quad * 8];
                sc[0][ct] = __builtin_amdgcn_mfma_f32_16x16x32_bf16(kf, qf[0][kb], sc[0][ct], 0, 0, 0);
                sc[1][ct] = __builtin_amdgcn_mfma_f32_16x16x32_bf16(kf, qf[1][kb], sc[1][ct], 0, 0, 0);
            }
        }

        // ---- online softmax (per-lane scalar per rt; keys spread over ct,r,quad)
        union PF { short8 s; uint u[4]; };
        PF pf[2][2]; // [rt][kb2]
        #pragma unroll
        for (int rt = 0; rt < 2; ++rt) {
            float tmax = -3.0e38f;
            #pragma unroll
            for (int ct = 0; ct < 4; ++ct)
                #pragma unroll
                for (int r = 0; r < 4; ++r) {
                    sc[rt][ct][r] *= SCALE;
                    tmax = fmaxf(tmax, sc[rt][ct][r]);
                }
            tmax = fmaxf(tmax, __shfl_xor(tmax, 16));
            tmax = fmaxf(tmax, __shfl_xor(tmax, 32));

            float mnew = fmaxf(m_run[rt], tmax);
            float al = __expf(m_run[rt] - mnew);
            m_run[rt] = mnew;

            float rsum = 0.f;
            #pragma unroll
            for (int ct = 0; ct < 4; ++ct)
                #pragma unroll
                for (int r = 0; r < 4; ++r) {
                    float p = __expf(sc[rt][ct][r] - mnew);
                    sc[rt][ct][r] = p;
                    rsum += p;
                }
            rsum += __shfl_xor(rsum, 16);
            rsum += __shfl_xor(rsum, 32);
            l_run[rt] = l_run[rt] * al + rsum;

            #pragma unroll
            for (int vt = 0; vt < 8; ++vt)
                #pragma unroll
                for (int r = 0; r < 4; ++r)
                    oa[rt][vt][r] *= al;

            // P^T B-frags: pure register repack thanks to the key permutation
            #pragma unroll
            for (int kb2 = 0; kb2 < 2; ++kb2)
                #pragma unroll
                for (int j2 = 0; j2 < 4; ++j2)
                    pf[rt][kb2].u[j2] = packbf(sc[rt][j2][2 * kb2], sc[rt][j2][2 * kb2 + 1]);
        }

        // ---- O^T += V^T · P^T
        #pragma unroll
        for (int kb2 = 0; kb2 < 2; ++kb2) {
            #pragma unroll
            for (int vt = 0; vt < 8; ++vt) {
                short8 vf = *(const short8*)&Vt[(vt * 16 + l16) * 72 + kb2 * 32 + quad * 8];
                oa[0][vt] = __builtin_amdgcn_mfma_f32_16x16x32_bf16(vf, pf[0][kb2].s, oa[0][vt], 0, 0, 0);
                oa[1][vt] = __builtin_amdgcn_mfma_f32_16x16x32_bf16(vf, pf[1][kb2].s, oa[1][vt], 0, 0, 0);
            }
        }
    }

    // ---- epilogue: transpose O^T -> O through reused LDS, coalesced store
    __syncthreads(); // everyone done with Ks/Vt
    ushort* ot = SH + wave * (32 * 136); // per-wave 32 rows x 136 us
    #pragma unroll
    for (int rt = 0; rt < 2; ++rt) {
        float inv = 1.0f / l_run[rt];
        #pragma unroll
        for (int vt = 0; vt < 8; ++vt)
            #pragma unroll
            for (int r = 0; r < 4; ++r)
                ot[(rt * 16 + l16) * 136 + vt * 16 + quad * 4 + r] = f2bf(oa[rt][vt][r] * inv);
    }
    // same-wave LDS ordering: no barrier needed
    #pragma unroll
    for (int pass = 0; pass < 8; ++pass) {
        int row_in = pass * 4 + (lane >> 4);
        int col8 = (lane & 15) * 8;
        uint4 v = *(const uint4*)&ot[row_in * 136 + col8];
        int srow = qrow_base + row_in;
        *(uint4*)(o_ws + (((size_t)b * S_SZ + srow) * NH + h) * DK + col8) = v;
    }
}

// ============================================================
// Kernel 4a: W_O [1024 k][1024 n] fp32 -> W_O^T bf16 [n][k] (unchanged)
// ============================================================
__global__ __launch_bounds__(256) void transpose_wo_kernel(
    const float* __restrict__ W_O, ushort* __restrict__ wot)
{
    __shared__ float t[32][33];
    const int tx = threadIdx.x & 31, ty = threadIdx.x >> 5;
    const int n0 = blockIdx.x * 32, k0 = blockIdx.y * 32;
    #pragma unroll
    for (int j = 0; j < 32; j += 8)
        t[ty + j][tx] = W_O[(size_t)(k0 + ty + j) * DM + n0 + tx];
    __syncthreads();
    #pragma unroll
    for (int j = 0; j < 32; j += 8)
        wot[(size_t)(n0 + ty + j) * DM + k0 + tx] = f2bf(t[tx][ty + j]);
}

// ============================================================
// Kernel 4b: out = o_ws @ W_O + b_O via MFMA (unchanged)
// ============================================================
__global__ __launch_bounds__(256) void out_gemm_mfma_kernel(
    const ushort* __restrict__ A,    // o_ws [8192][1024] bf16
    const ushort* __restrict__ BT,   // wot  [1024 n][1024 k] bf16
    const float* __restrict__ b_O, float* __restrict__ out)
{
    __shared__ __align__(16) ushort As[128 * 32];
    __shared__ __align__(16) ushort Bs[128 * 32];

    const int tid = threadIdx.x;
    const int wave = tid >> 6;
    const int lane = tid & 63;
    const int quad = lane >> 4;
    const int l16 = lane & 15;
    const int wr = wave >> 1, wc = wave & 1;

    const int n0 = blockIdx.x * 128;
    const int m0 = blockIdx.y * 128;

    const int lrow = lane >> 2;
    const int lseg = (lane & 3) * 8;

    floatx4 acc[4][4];
    #pragma unroll
    for (int mt = 0; mt < 4; ++mt)
        #pragma unroll
        for (int nt = 0; nt < 4; ++nt)
            acc[mt][nt] = (floatx4){0.f, 0.f, 0.f, 0.f};

    for (int k0 = 0; k0 < DM; k0 += 32) {
        __syncthreads();
        {
            const ushort* g0 = A + (size_t)(m0 + wave * 32 + lrow) * DM + k0 + lseg;
            glds16(g0, &As[(wave * 32) * 32]);
            const ushort* g1 = A + (size_t)(m0 + wave * 32 + 16 + lrow) * DM + k0 + lseg;
            glds16(g1, &As[(wave * 32 + 16) * 32]);
        }
        {
            const ushort* g0 = BT + (size_t)(n0 + wave * 32 + lrow) * DM + k0 + lseg;
            glds16(g0, &Bs[(wave * 32) * 32]);
            const ushort* g1 = BT + (size_t)(n0 + wave * 32 + 16 + lrow) * DM + k0 + lseg;
            glds16(g1, &Bs[(wave * 32 + 16) * 32]);
        }
        __syncthreads();

        short8 af[4], bf[4];
        #pragma unroll
        for (int mt = 0; mt < 4; ++mt)
            af[mt] = *(const short8*)&As[(wr * 64 + mt * 16 + l16) * 32 + quad * 8];
        #pragma unroll
        for (int nt = 0; nt < 4; ++nt)
            bf[nt] = *(const short8*)&Bs[(wc * 64 + nt * 16 + l16) * 32 + quad * 8];
        #pragma unroll
        for (int mt = 0; mt < 4; ++mt)
            #pragma unroll
            for (int nt = 0; nt < 4; ++nt)
                acc[mt][nt] = __builtin_amdgcn_mfma_f32_16x16x32_bf16(af[mt], bf[nt], acc[mt][nt], 0, 0, 0);
    }

    float bo[4];
    #pragma unroll
    for (int nt = 0; nt < 4; ++nt) bo[nt] = b_O[n0 + wc * 64 + nt * 16 + l16];

    #pragma unroll
    for (int mt = 0; mt < 4; ++mt) {
        #pragma unroll
        for (int r = 0; r < 4; ++r) {
            int row = m0 + wr * 64 + mt * 16 + quad * 4 + r;
            float* orow = out + (size_t)row * DM + n0 + wc * 64;
            #pragma unroll
            for (int nt = 0; nt < 4; ++nt)
                orow[nt * 16 + l16] = acc[mt][nt][r] + bo[nt];
        }
    }
}

// ============================================================
extern "C" void kernel_launch(void* const* d_in, const int* in_sizes, int n_in,
                              void* d_out, int out_size, void* d_ws, size_t ws_size,
                              hipStream_t stream) {
    (void)in_sizes; (void)n_in; (void)out_size; (void)ws_size;

    const float* h_t   = (const float*)d_in[0];
    const float* W_DQ  = (const float*)d_in[1];
    const float* b_DQ  = (const float*)d_in[2];
    const float* W_UQ  = (const float*)d_in[3];
    const float* b_UQ  = (const float*)d_in[4];
    const float* W_DKV = (const float*)d_in[5];
    const float* b_DKV = (const float*)d_in[6];
    const float* W_UK  = (const float*)d_in[7];
    const float* b_UK  = (const float*)d_in[8];
    const float* W_UV  = (const float*)d_in[9];
    const float* b_UV  = (const float*)d_in[10];
    const float* W_QR  = (const float*)d_in[11];
    const float* b_QR  = (const float*)d_in[12];
    const float* W_KR  = (const float*)d_in[13];
    const float* b_KR  = (const float*)d_in[14];
    const float* W_O   = (const float*)d_in[15];
    const float* b_O   = (const float*)d_in[16];

    float* c_q  = (float*)d_ws;
    float* c_kv = c_q + T_TOK * DC;
    float* k_r  = c_kv + T_TOK * DC;
    ushort* q_ws = (ushort*)(k_r + T_TOK * DC);
    ushort* k_ws = q_ws + (size_t)B_SZ * NH * S_SZ * DQK;
    ushort* v_ws = k_ws + (size_t)B_SZ * NH * S_SZ * DQK;
    ushort* o_ws = v_ws + (size_t)B_SZ * NH * S_SZ * DK;
    ushort* wot  = o_ws + (size_t)T_TOK * DM;

    float* out = (float*)d_out;

    latent_kernel<<<T_TOK / 32, 256, 0, stream>>>(
        h_t, W_DQ, b_DQ, W_DKV, b_DKV, W_KR, b_KR, c_q, c_kv, k_r);

    transpose_wo_kernel<<<dim3(32, 32), 256, 0, stream>>>(W_O, wot);

    build_qkv_kernel<<<T_TOK / 16, 256, 0, stream>>>(
        c_q, c_kv, k_r, W_UQ, b_UQ, W_UK, b_UK, W_UV, b_UV, W_QR, b_QR,
        q_ws, k_ws, v_ws);

    attn_mfma_kernel<<<dim3(S_SZ / 128, B_SZ * NH), 256, 0, stream>>>(
        q_ws, k_ws, v_ws, o_ws);

    out_gemm_mfma_kernel<<<dim3(DM / 128, T_TOK / 128), 256, 0, stream>>>(
        o_ws, wot, b_O, out);
}

// Round 7
// 420.593 us; speedup vs baseline: 6.3578x; 1.1030x over previous
//
#include <hip/hip_runtime.h>
#include <hip/hip_bf16.h>

// ---- problem constants ----
#define B_SZ 4
#define S_SZ 2048
#define DM   1024
#define NH   8
#define DK   128
#define DC   32
#define DHR  32
#define DQK  160            // DK + DHR
#define T_TOK (B_SZ * S_SZ) // 8192
#define SCALE 0.07905694150420949f // 1/sqrt(160)

typedef unsigned int uint;
typedef unsigned short ushort;
typedef __attribute__((ext_vector_type(8))) short short8;
typedef __attribute__((ext_vector_type(4))) float floatx4;

__device__ __forceinline__ float bf_lo(uint u) { return __uint_as_float(u << 16); }
__device__ __forceinline__ float bf_hi(uint u) { return __uint_as_float(u & 0xffff0000u); }
__device__ __forceinline__ ushort f2bf(float f) {
    uint u = __float_as_uint(f);
    uint r = u + 0x7fffu + ((u >> 16) & 1u);
    return (ushort)(r >> 16);
}
__device__ __forceinline__ uint packbf(float x, float y) {
    return (uint)f2bf(x) | ((uint)f2bf(y) << 16);
}

// async global->LDS, 16B per lane; lds dest = wave-uniform base + lane*16
__device__ __forceinline__ void glds16(const ushort* g, ushort* l) {
    __builtin_amdgcn_global_load_lds(
        (const __attribute__((address_space(1))) uint*)g,
        (__attribute__((address_space(3))) uint*)l, 16, 0, 0);
}

// ============================================================
// Kernel 1: c_q, c_kv, k_r  = h_t @ {W_DQ, W_DKV, W_KR} + bias
// (unchanged)
// ============================================================
__global__ __launch_bounds__(256) void latent_kernel(
    const float* __restrict__ h_t,
    const float* __restrict__ W_DQ, const float* __restrict__ b_DQ,
    const float* __restrict__ W_DKV, const float* __restrict__ b_DKV,
    const float* __restrict__ W_KR, const float* __restrict__ b_KR,
    float* __restrict__ c_q, float* __restrict__ c_kv, float* __restrict__ k_r)
{
    __shared__ __align__(16) float hs[32 * 33];
    __shared__ __align__(16) float wq[32 * 32];
    __shared__ __align__(16) float wkv[32 * 32];
    __shared__ __align__(16) float wkr[32 * 32];

    const int tid = threadIdx.x;
    const int t0 = blockIdx.x * 32;
    const int t = tid & 31;
    const int g = tid >> 5;

    float acc_q[4] = {0.f, 0.f, 0.f, 0.f};
    float acc_kv[4] = {0.f, 0.f, 0.f, 0.f};
    float acc_kr[4] = {0.f, 0.f, 0.f, 0.f};

    const int lr = tid >> 3;
    const int lc = (tid & 7) * 4;

    for (int k0 = 0; k0 < DM; k0 += 32) {
        __syncthreads();
        {
            float4 v = *(const float4*)&h_t[(size_t)(t0 + lr) * DM + k0 + lc];
            hs[lr * 33 + lc + 0] = v.x;
            hs[lr * 33 + lc + 1] = v.y;
            hs[lr * 33 + lc + 2] = v.z;
            hs[lr * 33 + lc + 3] = v.w;
        }
        {
            float4 a = *(const float4*)&W_DQ[(size_t)(k0 + lr) * 32 + lc];
            wq[lr * 32 + lc + 0] = a.x; wq[lr * 32 + lc + 1] = a.y;
            wq[lr * 32 + lc + 2] = a.z; wq[lr * 32 + lc + 3] = a.w;
            float4 b = *(const float4*)&W_DKV[(size_t)(k0 + lr) * 32 + lc];
            wkv[lr * 32 + lc + 0] = b.x; wkv[lr * 32 + lc + 1] = b.y;
            wkv[lr * 32 + lc + 2] = b.z; wkv[lr * 32 + lc + 3] = b.w;
            float4 c = *(const float4*)&W_KR[(size_t)(k0 + lr) * 32 + lc];
            wkr[lr * 32 + lc + 0] = c.x; wkr[lr * 32 + lc + 1] = c.y;
            wkr[lr * 32 + lc + 2] = c.z; wkr[lr * 32 + lc + 3] = c.w;
        }
        __syncthreads();
        #pragma unroll 8
        for (int kk = 0; kk < 32; ++kk) {
            float a = hs[t * 33 + kk];
            #pragma unroll
            for (int cc = 0; cc < 4; ++cc) {
                int c = g * 4 + cc;
                acc_q[cc] += a * wq[kk * 32 + c];
                acc_kv[cc] += a * wkv[kk * 32 + c];
                acc_kr[cc] += a * wkr[kk * 32 + c];
            }
        }
    }
    #pragma unroll
    for (int cc = 0; cc < 4; ++cc) {
        int c = g * 4 + cc;
        int idx = (t0 + t) * 32 + c;
        c_q[idx] = acc_q[cc] + b_DQ[c];
        c_kv[idx] = acc_kv[cc] + b_DKV[c];
        k_r[idx] = acc_kr[cc] + b_KR[c];
    }
}

// ============================================================
// Kernel 2: build q, k, v (bf16) in [bh][s][d] layout. (unchanged)
// ============================================================
__global__ __launch_bounds__(256) void build_qkv_kernel(
    const float* __restrict__ c_q, const float* __restrict__ c_kv,
    const float* __restrict__ k_r,
    const float* __restrict__ W_UQ, const float* __restrict__ b_UQ,
    const float* __restrict__ W_UK, const float* __restrict__ b_UK,
    const float* __restrict__ W_UV, const float* __restrict__ b_UV,
    const float* __restrict__ W_QR, const float* __restrict__ b_QR,
    ushort* __restrict__ q_ws, ushort* __restrict__ k_ws, ushort* __restrict__ v_ws)
{
    __shared__ __align__(16) float cb[16 * 96];
    const int tid = threadIdx.x;
    const int t0 = blockIdx.x * 16;

    for (int i = tid; i < 512; i += 256) {
        int tt = i >> 5, c = i & 31;
        cb[tt * 96 + c] = c_q[(t0 + tt) * 32 + c];
        cb[tt * 96 + 32 + c] = c_kv[(t0 + tt) * 32 + c];
        cb[tt * 96 + 64 + c] = k_r[(t0 + tt) * 32 + c];
    }
    __syncthreads();

    for (int i = 0; i < 14; ++i) {
        int e = i * 256 + tid;
        int h = e / 448;
        int r = e - h * 448;

        float acc[16];
        if (r >= 288 && r < 320) {
            #pragma unroll
            for (int tt = 0; tt < 16; ++tt) acc[tt] = cb[tt * 96 + 64 + (r - 288)];
        } else {
            const float* W; const float* bias; int stride, col, coff;
            if (r < 128)      { W = W_UQ; stride = 1024; col = h * 128 + r;        coff = 0;  bias = b_UQ; }
            else if (r < 160) { W = W_QR; stride = 256;  col = h * 32 + (r - 128); coff = 0;  bias = b_QR; }
            else if (r < 288) { W = W_UK; stride = 1024; col = h * 128 + (r - 160);coff = 32; bias = b_UK; }
            else              { W = W_UV; stride = 1024; col = h * 128 + (r - 320);coff = 32; bias = b_UV; }
            float bv = bias[col];
            #pragma unroll
            for (int tt = 0; tt < 16; ++tt) acc[tt] = bv;
            for (int kk = 0; kk < 32; ++kk) {
                float w = W[kk * stride + col];
                #pragma unroll
                for (int tt = 0; tt < 16; ++tt) acc[tt] += cb[tt * 96 + coff + kk] * w;
            }
        }
        #pragma unroll
        for (int tt = 0; tt < 16; ++tt) {
            int tok = t0 + tt;
            int b = tok >> 11, s = tok & 2047;
            int bh = b * NH + h;
            ushort val = f2bf(acc[tt]);
            if (r < 160)      q_ws[((size_t)bh * S_SZ + s) * DQK + r] = val;
            else if (r < 320) k_ws[((size_t)bh * S_SZ + s) * DQK + (r - 160)] = val;
            else              v_ws[((size_t)bh * S_SZ + s) * DK + (r - 320)] = val;
        }
    }
}

// ============================================================
// Kernel 3: transposed-score MFMA flash attention, 512 threads.
// 8 waves x 16 Q rows = 128 rows/block (same grid, same staging,
// 2x the waves/CU: 16 waves/CU = 4/SIMD for MFMA<->VALU overlap).
// Sc^T = K·Q^T ; O^T = V^T·P^T ; key permutation makes P^T a pure
// register repack (see round-6 comments). LDS 39936 B.
// Grid: (S/128, B*H) = (16, 32).
// ============================================================
__global__ __launch_bounds__(512, 4) void attn_mfma_kernel(
    const ushort* __restrict__ q_ws, const ushort* __restrict__ k_ws,
    const ushort* __restrict__ v_ws, ushort* __restrict__ o_ws)
{
    __shared__ __align__(16) ushort SH[64 * 168 + 128 * 72]; // 39936 B
    ushort* const Ks = SH;             // [score-row][d], stride 168
    ushort* const Vt = SH + 64 * 168;  // [d][key], stride 72

    const int tid = threadIdx.x;
    const int wave = tid >> 6;   // 0..7
    const int lane = tid & 63;
    const int quad = lane >> 4;
    const int l16 = lane & 15;

    const int bh = blockIdx.y;
    const int b = bh >> 3, h = bh & 7;
    const int s0 = blockIdx.x * 128;
    const int qrow_base = s0 + wave * 16;

    // Q fragments (serve as B-operand of the swapped MFMA)
    short8 qf[5];
    #pragma unroll
    for (int kb = 0; kb < 5; ++kb) {
        const ushort* p = q_ws + ((size_t)bh * S_SZ + qrow_base + l16) * DQK
                        + kb * 32 + quad * 8;
        qf[kb] = *(const short8*)p;
    }

    floatx4 oa[8];   // O^T: col(l16)=qrow, row(quad*4+r)=d
    #pragma unroll
    for (int vt = 0; vt < 8; ++vt)
        oa[vt] = (floatx4){0.f, 0.f, 0.f, 0.f};

    float m_run = -3.0e38f, l_run = 0.f;

    for (int kt = 0; kt < S_SZ / 64; ++kt) {
        const int k0 = kt * 64;
        __syncthreads(); // all waves done reading prior tile

        // ---- stage K with score-slot permutation
        {
            const uint4* kg = (const uint4*)(k_ws + (size_t)bh * S_SZ * DQK + (size_t)k0 * DQK);
            for (int i = tid; i < 1280; i += 512) {
                int row = i / 20, seg = i - row * 20;
                int prow = ((row & 2) >> 1) * 32 + ((row >> 2) & 3) * 8
                         + ((row >> 4) << 1) + (row & 1);
                *(uint4*)&Ks[row * 168 + seg * 8] = kg[prow * 20 + seg];
            }
        }
        // ---- stage V transposed; 512 thr: lane=d-pair, wave=key-quad
        {
            const uint* vg = (const uint*)(v_ws + (size_t)bh * S_SZ * DK + (size_t)k0 * DK);
            uint* vt32 = (uint*)Vt;
            const int dp = lane;
            const int kq = wave;
            uint lo[4], hi[4];
            #pragma unroll
            for (int c = 0; c < 4; ++c) {
                int kp = kq * 4 + c;
                uint a  = vg[(2 * kp) * 64 + dp];
                uint bb = vg[(2 * kp + 1) * 64 + dp];
                lo[c] = (a & 0xffffu) | (bb << 16);
                hi[c] = (a >> 16) | (bb & 0xffff0000u);
            }
            *(uint4*)&vt32[(2 * dp) * 36 + kq * 4]     = make_uint4(lo[0], lo[1], lo[2], lo[3]);
            *(uint4*)&vt32[(2 * dp + 1) * 36 + kq * 4] = make_uint4(hi[0], hi[1], hi[2], hi[3]);
        }
        __syncthreads();

        // ---- Sc^T = K·Q^T : D[m=key(slot)][n=qrow]
        floatx4 sc[4];
        #pragma unroll
        for (int ct = 0; ct < 4; ++ct) {
            sc[ct] = (floatx4){0.f, 0.f, 0.f, 0.f};
            #pragma unroll
            for (int kb = 0; kb < 5; ++kb) {
                short8 kf = *(const short8*)&Ks[(ct * 16 + l16) * 168 + kb * 32 + quad * 8];
                sc[ct] = __builtin_amdgcn_mfma_f32_16x16x32_bf16(kf, qf[kb], sc[ct], 0, 0, 0);
            }
        }

        // ---- online softmax (per-lane scalar; keys spread over ct,r,quad)
        union PF { short8 s; uint u[4]; };
        PF pf[2];
        {
            float tmax = -3.0e38f;
            #pragma unroll
            for (int ct = 0; ct < 4; ++ct)
                #pragma unroll
                for (int r = 0; r < 4; ++r) {
                    sc[ct][r] *= SCALE;
                    tmax = fmaxf(tmax, sc[ct][r]);
                }
            tmax = fmaxf(tmax, __shfl_xor(tmax, 16));
            tmax = fmaxf(tmax, __shfl_xor(tmax, 32));

            float mnew = fmaxf(m_run, tmax);
            float al = __expf(m_run - mnew);
            m_run = mnew;

            float rsum = 0.f;
            #pragma unroll
            for (int ct = 0; ct < 4; ++ct)
                #pragma unroll
                for (int r = 0; r < 4; ++r) {
                    float p = __expf(sc[ct][r] - mnew);
                    sc[ct][r] = p;
                    rsum += p;
                }
            rsum += __shfl_xor(rsum, 16);
            rsum += __shfl_xor(rsum, 32);
            l_run = l_run * al + rsum;

            #pragma unroll
            for (int vt = 0; vt < 8; ++vt)
                #pragma unroll
                for (int r = 0; r < 4; ++r)
                    oa[vt][r] *= al;

            #pragma unroll
            for (int kb2 = 0; kb2 < 2; ++kb2)
                #pragma unroll
                for (int j2 = 0; j2 < 4; ++j2)
                    pf[kb2].u[j2] = packbf(sc[j2][2 * kb2], sc[j2][2 * kb2 + 1]);
        }

        // ---- O^T += V^T · P^T
        #pragma unroll
        for (int kb2 = 0; kb2 < 2; ++kb2) {
            #pragma unroll
            for (int vt = 0; vt < 8; ++vt) {
                short8 vf = *(const short8*)&Vt[(vt * 16 + l16) * 72 + kb2 * 32 + quad * 8];
                oa[vt] = __builtin_amdgcn_mfma_f32_16x16x32_bf16(vf, pf[kb2].s, oa[vt], 0, 0, 0);
            }
        }
    }

    // ---- epilogue: transpose O^T -> O through reused LDS, coalesced store
    __syncthreads(); // everyone done with Ks/Vt
    ushort* ot = SH + wave * (16 * 136); // per-wave 16 rows x 136 us (34816 B total)
    uint* ot32 = (uint*)ot;
    {
        float inv = 1.0f / l_run;
        #pragma unroll
        for (int vt = 0; vt < 8; ++vt)
            #pragma unroll
            for (int rp = 0; rp < 2; ++rp)
                ot32[l16 * 68 + vt * 8 + quad * 2 + rp] =
                    packbf(oa[vt][2 * rp] * inv, oa[vt][2 * rp + 1] * inv);
    }
    // same-wave LDS ordering: no barrier needed
    #pragma unroll
    for (int pass = 0; pass < 4; ++pass) {
        int row_in = pass * 4 + (lane >> 4);
        int col8 = (lane & 15) * 8;
        uint4 v = *(const uint4*)&ot[row_in * 136 + col8];
        int srow = qrow_base + row_in;
        *(uint4*)(o_ws + (((size_t)b * S_SZ + srow) * NH + h) * DK + col8) = v;
    }
}

// ============================================================
// Kernel 4a: W_O [1024 k][1024 n] fp32 -> W_O^T bf16 [n][k] (unchanged)
// ============================================================
__global__ __launch_bounds__(256) void transpose_wo_kernel(
    const float* __restrict__ W_O, ushort* __restrict__ wot)
{
    __shared__ float t[32][33];
    const int tx = threadIdx.x & 31, ty = threadIdx.x >> 5;
    const int n0 = blockIdx.x * 32, k0 = blockIdx.y * 32;
    #pragma unroll
    for (int j = 0; j < 32; j += 8)
        t[ty + j][tx] = W_O[(size_t)(k0 + ty + j) * DM + n0 + tx];
    __syncthreads();
    #pragma unroll
    for (int j = 0; j < 32; j += 8)
        wot[(size_t)(n0 + ty + j) * DM + k0 + tx] = f2bf(t[tx][ty + j]);
}

// ============================================================
// Kernel 4b: out = o_ws @ W_O + b_O via MFMA (unchanged)
// ============================================================
__global__ __launch_bounds__(256) void out_gemm_mfma_kernel(
    const ushort* __restrict__ A,    // o_ws [8192][1024] bf16
    const ushort* __restrict__ BT,   // wot  [1024 n][1024 k] bf16
    const float* __restrict__ b_O, float* __restrict__ out)
{
    __shared__ __align__(16) ushort As[128 * 32];
    __shared__ __align__(16) ushort Bs[128 * 32];

    const int tid = threadIdx.x;
    const int wave = tid >> 6;
    const int lane = tid & 63;
    const int quad = lane >> 4;
    const int l16 = lane & 15;
    const int wr = wave >> 1, wc = wave & 1;

    const int n0 = blockIdx.x * 128;
    const int m0 = blockIdx.y * 128;

    const int lrow = lane >> 2;
    const int lseg = (lane & 3) * 8;

    floatx4 acc[4][4];
    #pragma unroll
    for (int mt = 0; mt < 4; ++mt)
        #pragma unroll
        for (int nt = 0; nt < 4; ++nt)
            acc[mt][nt] = (floatx4){0.f, 0.f, 0.f, 0.f};

    for (int k0 = 0; k0 < DM; k0 += 32) {
        __syncthreads();
        {
            const ushort* g0 = A + (size_t)(m0 + wave * 32 + lrow) * DM + k0 + lseg;
            glds16(g0, &As[(wave * 32) * 32]);
            const ushort* g1 = A + (size_t)(m0 + wave * 32 + 16 + lrow) * DM + k0 + lseg;
            glds16(g1, &As[(wave * 32 + 16) * 32]);
        }
        {
            const ushort* g0 = BT + (size_t)(n0 + wave * 32 + lrow) * DM + k0 + lseg;
            glds16(g0, &Bs[(wave * 32) * 32]);
            const ushort* g1 = BT + (size_t)(n0 + wave * 32 + 16 + lrow) * DM + k0 + lseg;
            glds16(g1, &Bs[(wave * 32 + 16) * 32]);
        }
        __syncthreads();

        short8 af[4], bf[4];
        #pragma unroll
        for (int mt = 0; mt < 4; ++mt)
            af[mt] = *(const short8*)&As[(wr * 64 + mt * 16 + l16) * 32 + quad * 8];
        #pragma unroll
        for (int nt = 0; nt < 4; ++nt)
            bf[nt] = *(const short8*)&Bs[(wc * 64 + nt * 16 + l16) * 32 + quad * 8];
        #pragma unroll
        for (int mt = 0; mt < 4; ++mt)
            #pragma unroll
            for (int nt = 0; nt < 4; ++nt)
                acc[mt][nt] = __builtin_amdgcn_mfma_f32_16x16x32_bf16(af[mt], bf[nt], acc[mt][nt], 0, 0, 0);
    }

    float bo[4];
    #pragma unroll
    for (int nt = 0; nt < 4; ++nt) bo[nt] = b_O[n0 + wc * 64 + nt * 16 + l16];

    #pragma unroll
    for (int mt = 0; mt < 4; ++mt) {
        #pragma unroll
        for (int r = 0; r < 4; ++r) {
            int row = m0 + wr * 64 + mt * 16 + quad * 4 + r;
            float* orow = out + (size_t)row * DM + n0 + wc * 64;
            #pragma unroll
            for (int nt = 0; nt < 4; ++nt)
                orow[nt * 16 + l16] = acc[mt][nt][r] + bo[nt];
        }
    }
}

// ============================================================
extern "C" void kernel_launch(void* const* d_in, const int* in_sizes, int n_in,
                              void* d_out, int out_size, void* d_ws, size_t ws_size,
                              hipStream_t stream) {
    (void)in_sizes; (void)n_in; (void)out_size; (void)ws_size;

    const float* h_t   = (const float*)d_in[0];
    const float* W_DQ  = (const float*)d_in[1];
    const float* b_DQ  = (const float*)d_in[2];
    const float* W_UQ  = (const float*)d_in[3];
    const float* b_UQ  = (const float*)d_in[4];
    const float* W_DKV = (const float*)d_in[5];
    const float* b_DKV = (const float*)d_in[6];
    const float* W_UK  = (const float*)d_in[7];
    const float* b_UK  = (const float*)d_in[8];
    const float* W_UV  = (const float*)d_in[9];
    const float* b_UV  = (const float*)d_in[10];
    const float* W_QR  = (const float*)d_in[11];
    const float* b_QR  = (const float*)d_in[12];
    const float* W_KR  = (const float*)d_in[13];
    const float* b_KR  = (const float*)d_in[14];
    const float* W_O   = (const float*)d_in[15];
    const float* b_O   = (const float*)d_in[16];

    float* c_q  = (float*)d_ws;
    float* c_kv = c_q + T_TOK * DC;
    float* k_r  = c_kv + T_TOK * DC;
    ushort* q_ws = (ushort*)(k_r + T_TOK * DC);
    ushort* k_ws = q_ws + (size_t)B_SZ * NH * S_SZ * DQK;
    ushort* v_ws = k_ws + (size_t)B_SZ * NH * S_SZ * DQK;
    ushort* o_ws = v_ws + (size_t)B_SZ * NH * S_SZ * DK;
    ushort* wot  = o_ws + (size_t)T_TOK * DM;

    float* out = (float*)d_out;

    latent_kernel<<<T_TOK / 32, 256, 0, stream>>>(
        h_t, W_DQ, b_DQ, W_DKV, b_DKV, W_KR, b_KR, c_q, c_kv, k_r);

    transpose_wo_kernel<<<dim3(32, 32), 256, 0, stream>>>(W_O, wot);

    build_qkv_kernel<<<T_TOK / 16, 256, 0, stream>>>(
        c_q, c_kv, k_r, W_UQ, b_UQ, W_UK, b_UK, W_UV, b_UV, W_QR, b_QR,
        q_ws, k_ws, v_ws);

    attn_mfma_kernel<<<dim3(S_SZ / 128, B_SZ * NH), 512, 0, stream>>>(
        q_ws, k_ws, v_ws, o_ws);

    out_gemm_mfma_kernel<<<dim3(DM / 128, T_TOK / 128), 256, 0, stream>>>(
        o_ws, wot, b_O, out);
}